// Round 12
// baseline (469.399 us; speedup 1.0000x reference)
//
#include <hip/hip_runtime.h>

// Problem constants (match reference setup_inputs)
constexpr int B = 64, T = 256, M = 16, A = 32, H = 64;
constexpr int ROWB = 11264;   // G row stride bytes: 10368 used (81g x 64gc x bf16) + pad = 11 x 1KB

typedef __attribute__((ext_vector_type(8))) short bf16x8;
typedef __attribute__((ext_vector_type(4))) float f32x4;

// ws layout
constexpr size_t OW = 0;                               // Wb  bf16 [5184][32]
constexpr size_t OX = 332800;                          // xb  bf16 [B*T][32]
constexpr size_t OB = OX + (size_t)B * T * A * 2;      // bias f32 [5184]
constexpr size_t OG = OB + 21504;                      // G rows (row-major bf16)

__device__ __forceinline__ float blo(unsigned u) { return __builtin_bit_cast(float, u << 16); }
// raw-hi: use packed word directly as f32; low 16 garbage bits are mantissa
// bits 9..24 => <= 2^-9 relative perturbation (half of bf16 quant noise).
__device__ __forceinline__ float bhr(unsigned u) { return __builtin_bit_cast(float, u); }
__device__ __forceinline__ float bhi(unsigned u) { return __builtin_bit_cast(float, u & 0xffff0000u); }

// ---------------------------------------------------------------------------
// Prep: convert W (Wj|Wr|Wo) and x_a to bf16 (RNE); concat biases to f32.
// ---------------------------------------------------------------------------
__global__ __launch_bounds__(256) void prep_kernel(
    const float* __restrict__ x_a,
    const float* __restrict__ Wj, const float* __restrict__ Wr,
    const float* __restrict__ Wo,
    const float* __restrict__ bj, const float* __restrict__ br,
    const float* __restrict__ bo, unsigned char* ws)
{
    const int nW = 5184 * 32, nX = B * T * A, nB = 5184;
    int idx = blockIdx.x * 256 + threadIdx.x;
    if (idx >= nW + nX + nB) return;
    if (idx < nW + nX) {
        float v;
        ushort* dst;
        if (idx < nW) {
            int row = idx >> 5;
            v = (row < 1024) ? Wj[idx] : (row < 5120) ? Wr[idx - 1024 * 32] : Wo[idx - 5120 * 32];
            dst = (ushort*)(ws + OW) + idx;
        } else {
            v = x_a[idx - nW];
            dst = (ushort*)(ws + OX) + (idx - nW);
        }
        unsigned u = __builtin_bit_cast(unsigned, v);
        *dst = (ushort)((u + 0x7fffu + ((u >> 16) & 1u)) >> 16);   // RNE
    } else {
        int row = idx - nW - nX;
        float v = (row < 1024) ? bj[row] : (row < 5120) ? br[row - 1024] : bo[row - 5120];
        ((float*)(ws + OB))[row] = v;
    }
}

// ---------------------------------------------------------------------------
// Gate kernel (MFMA + LDS transpose; unchanged from R11 -- fast & correct):
// block = 32 rows x all 81 groups. Swapped GEMM: D[gc][t] = mfma(A=W, B=x);
// lane holds (t = lane&15, gc = 4*(lane>>4)+reg). Per group-PAIR the wave
// stages 2x(16t x 128gc) bf16 tiles in LDS, stores row-major G in 256B runs.
// ---------------------------------------------------------------------------
__global__ __launch_bounds__(256) void gate_kernel(
    unsigned char* ws, int t0, int chunk)
{
    const int tid = threadIdx.x, lane = tid & 63, wv = tid >> 6;
    const int l15 = lane & 15, l4 = lane >> 4;
    const ushort* Wb = (const ushort*)(ws + OW);
    const ushort* xb = (const ushort*)(ws + OX);
    const float*  bc = (const float*)(ws + OB);
    unsigned char* G = ws + OG;

    __shared__ ushort tr[4][32][152];

    const int r0 = blockIdx.x * 32;     // 32 consecutive rows, same batch (chunk % 32 == 0)
    const int bb = r0 / chunk, tcc = r0 % chunk;
    const long xrow0 = (long)bb * T + t0 + tcc;

    const bf16x8 bx0 = *(const bf16x8*)(xb + (xrow0 + l15) * 32 + l4 * 8);
    const bf16x8 bx1 = *(const bf16x8*)(xb + (xrow0 + 16 + l15) * 32 + l4 * 8);

    const int p0 = wv * 10;
    const int pend = p0 + ((wv == 3) ? 11 : 10);   // wave3: pairs 30..39 + (80,dup)
    const int rr = lane >> 4, c16 = lane & 15;
    const f32x4 zero = {0.f, 0.f, 0.f, 0.f};

    for (int p = p0; p < pend; ++p) {
        #pragma unroll
        for (int gl = 0; gl < 2; ++gl) {
            int g = 2 * p + gl;
            if (g > 80) g = 80;        // duplicate o-gate into the pad slot
            f32x4 d0[4], d1[4];
            #pragma unroll
            for (int ct = 0; ct < 4; ++ct) {
                const bf16x8 aW =
                    *(const bf16x8*)(Wb + (size_t)(g * 64 + ct * 16 + l15) * 32 + l4 * 8);
                d0[ct] = __builtin_amdgcn_mfma_f32_16x16x32_bf16(aW, bx0, zero, 0, 0, 0);
                d1[ct] = __builtin_amdgcn_mfma_f32_16x16x32_bf16(aW, bx1, zero, 0, 0, 0);
                const float4 bv = *(const float4*)(bc + g * 64 + ct * 16 + l4 * 4);
                d0[ct][0] += bv.x; d0[ct][1] += bv.y; d0[ct][2] += bv.z; d0[ct][3] += bv.w;
                d1[ct][0] += bv.x; d1[ct][1] += bv.y; d1[ct][2] += bv.z; d1[ct][3] += bv.w;
            }

            if (g < 80) {   // softmax over 64 gate-cols: lane-local 16 + shfl(16,32)
                float s0 = 0.f, s1 = 0.f;
                #pragma unroll
                for (int ct = 0; ct < 4; ++ct)
                    #pragma unroll
                    for (int j = 0; j < 4; ++j) {
                        d0[ct][j] = __expf(d0[ct][j]); s0 += d0[ct][j];
                        d1[ct][j] = __expf(d1[ct][j]); s1 += d1[ct][j];
                    }
                s0 += __shfl_xor(s0, 16); s0 += __shfl_xor(s0, 32);
                s1 += __shfl_xor(s1, 16); s1 += __shfl_xor(s1, 32);
                const float i0 = __fdividef(1.f, s0), i1 = __fdividef(1.f, s1);
                #pragma unroll
                for (int ct = 0; ct < 4; ++ct)
                    #pragma unroll
                    for (int j = 0; j < 4; ++j) { d0[ct][j] *= i0; d1[ct][j] *= i1; }
            } else {        // out-gate sigmoid
                #pragma unroll
                for (int ct = 0; ct < 4; ++ct)
                    #pragma unroll
                    for (int j = 0; j < 4; ++j) {
                        d0[ct][j] = __fdividef(1.f, 1.f + __expf(-d0[ct][j]));
                        d1[ct][j] = __fdividef(1.f, 1.f + __expf(-d1[ct][j]));
                    }
            }

            #pragma unroll
            for (int ct = 0; ct < 4; ++ct) {   // pack bf16, write LDS tiles
                unsigned lo0, hi0, lo1, hi1;
                asm volatile("v_cvt_pk_bf16_f32 %0, %1, %2" : "=v"(lo0) : "v"(d0[ct][0]), "v"(d0[ct][1]));
                asm volatile("v_cvt_pk_bf16_f32 %0, %1, %2" : "=v"(hi0) : "v"(d0[ct][2]), "v"(d0[ct][3]));
                asm volatile("v_cvt_pk_bf16_f32 %0, %1, %2" : "=v"(lo1) : "v"(d1[ct][0]), "v"(d1[ct][1]));
                asm volatile("v_cvt_pk_bf16_f32 %0, %1, %2" : "=v"(hi1) : "v"(d1[ct][2]), "v"(d1[ct][3]));
                *(uint2*)&tr[wv][l15][gl * 64 + ct * 16 + l4 * 4]      = make_uint2(lo0, hi0);
                *(uint2*)&tr[wv][16 + l15][gl * 64 + ct * 16 + l4 * 4] = make_uint2(lo1, hi1);
            }
        }

        // same-wave DS write->read ordering, then coalesced 256B-run stores
        asm volatile("s_waitcnt lgkmcnt(0)" ::: "memory");
        __builtin_amdgcn_sched_barrier(0);
        const size_t gbyte = (size_t)p * 256;
        #pragma unroll
        for (int i = 0; i < 8; ++i) {            // 2 tiles x 4 row-quads
            const int row = (i >> 2) * 16 + (i & 3) * 4 + rr;
            uint4 v = *(const uint4*)&tr[wv][row][c16 * 8];
            *(uint4*)(G + (size_t)(r0 + row) * ROWB + gbyte + c16 * 16) = v;
        }
        asm volatile("s_waitcnt lgkmcnt(0)" ::: "memory");  // reads done before next pass
        __builtin_amdgcn_sched_barrier(0);
    }
}

// ---------------------------------------------------------------------------
// Scan kernel: R9-proven pipeline shape (3-deep, waits 22/11/0, chunk=64).
// One wave per batch; 11x1KB contiguous DMA per step; bf16 b64 reads with
// raw-hi extraction (J/R); shfl_xor reduce; fp32 math.
// ---------------------------------------------------------------------------
__global__ __launch_bounds__(64, 1) void scan_kernel(
    const unsigned char* __restrict__ ws,
    const float* __restrict__ x_m,
    const float* __restrict__ Wfc, const float* __restrict__ bfc,
    float* __restrict__ out, int t0, int chunk, int first)
{
    const int b = blockIdx.x, l = threadIdx.x;
    const int q = l & 15, hr = l >> 4;
    const unsigned char* G = ws + OG;

    __shared__ __align__(16) unsigned char buf[3][ROWB];    // 33.8KB
    __shared__ __align__(16) float c_sh[64];
    __shared__ __align__(16) float xm_s[1024];              // chunk<=64

    float* cbase = out + B;   // c region: cbase[(b*T + t)*H + k]

    {   // stage x_m chunk
        const float4* src = (const float4*)(x_m + ((size_t)b * T + t0) * M);
        float4* dst = (float4*)xm_s;
        for (int i = l; i < chunk * 4; i += 64) dst[i] = src[i];
    }
    c_sh[l] = first ? 0.f : cbase[((size_t)b * T + (t0 - 1)) * H + l];
    const float4 wfc4 = *(const float4*)&Wfc[q * 4];
    const float bfc0 = bfc[0];
    asm volatile("s_waitcnt vmcnt(0) lgkmcnt(0)" ::: "memory");

#define DMA(tc_)                                                                \
    {                                                                           \
        const unsigned char* rp_ = G + (size_t)(b * chunk + (tc_)) * ROWB;      \
        unsigned char* lb_ = &buf[(tc_) % 3][0];                                \
        _Pragma("unroll")                                                       \
        for (int i_ = 0; i_ < 11; ++i_)                                         \
            __builtin_amdgcn_global_load_lds(                                   \
                (const __attribute__((address_space(1))) unsigned int*)         \
                    (rp_ + i_ * 1024 + l * 16),                                 \
                (__attribute__((address_space(3))) unsigned int*)               \
                    (lb_ + i_ * 1024), 16, 0, 0);                               \
    }

    DMA(0); DMA(1); DMA(2);

    for (int tc = 0; tc < chunk; ++tc) {
        if (tc + 3 <= chunk)      asm volatile("s_waitcnt vmcnt(22)" ::: "memory");
        else if (tc + 2 == chunk) asm volatile("s_waitcnt vmcnt(11)" ::: "memory");
        else                      asm volatile("s_waitcnt vmcnt(0)"  ::: "memory");
        __builtin_amdgcn_sched_barrier(0);

        const ushort* bp = (const ushort*)&buf[tc % 3][0];

        float cc[16];
        #pragma unroll
        for (int i = 0; i < 16; ++i) cc[i] = c_sh[hr * 16 + i];
        float xm[4];
        #pragma unroll
        for (int j = 0; j < 4; ++j) xm[j] = xm_s[tc * 16 + hr * 4 + j];

        float a0 = 0.f, a1 = 0.f, a2 = 0.f, a3 = 0.f;
        #pragma unroll
        for (int j = 0; j < 4; ++j) {   // J: g = hr*4+j
            const uint2 u = *(const uint2*)(bp + (hr * 4 + j) * 64 + q * 4);
            a0 += xm[j] * blo(u.x); a1 += xm[j] * bhr(u.x);
            a2 += xm[j] * blo(u.y); a3 += xm[j] * bhr(u.y);
        }
        float e0 = 0.f, e1 = 0.f, e2 = 0.f, e3 = 0.f;   // split accumulators
        #pragma unroll
        for (int i = 0; i < 16; i += 2) {  // R: h = hr*16+i
            const uint2 u0 = *(const uint2*)(bp + 1024 + (hr * 16 + i) * 64 + q * 4);
            const uint2 u1 = *(const uint2*)(bp + 1024 + (hr * 16 + i + 1) * 64 + q * 4);
            a0 += cc[i] * blo(u0.x);     a1 += cc[i] * bhr(u0.x);
            a2 += cc[i] * blo(u0.y);     a3 += cc[i] * bhr(u0.y);
            e0 += cc[i + 1] * blo(u1.x); e1 += cc[i + 1] * bhr(u1.x);
            e2 += cc[i + 1] * blo(u1.y); e3 += cc[i + 1] * bhr(u1.y);
        }
        a0 += e0; a1 += e1; a2 += e2; a3 += e3;
        const uint2 uo = *(const uint2*)(bp + 5120 + q * 4);
        const float o0 = blo(uo.x), o1 = bhi(uo.x), o2 = blo(uo.y), o3 = bhi(uo.y);

        a0 += __shfl_xor(a0, 16); a1 += __shfl_xor(a1, 16);
        a2 += __shfl_xor(a2, 16); a3 += __shfl_xor(a3, 16);
        a0 += __shfl_xor(a0, 32); a1 += __shfl_xor(a1, 32);
        a2 += __shfl_xor(a2, 32); a3 += __shfl_xor(a3, 32);

        const float cn0 = (1.f - o0) * a0;
        const float cn1 = (1.f - o1) * a1;
        const float cn2 = (1.f - o2) * a2;
        const float cn3 = (1.f - o3) * a3;

        if (hr == 0) {
            *(float4*)&c_sh[q * 4] = make_float4(cn0, cn1, cn2, cn3);
            *(float4*)(cbase + ((size_t)b * T + t0 + tc) * H + q * 4) =
                make_float4(cn0, cn1, cn2, cn3);
        }
        if (t0 + tc == T - 1) {
            float v = o0 * a0 * wfc4.x + o1 * a1 * wfc4.y +
                      o2 * a2 * wfc4.z + o3 * a3 * wfc4.w;
            v += __shfl_xor(v, 1); v += __shfl_xor(v, 2);
            v += __shfl_xor(v, 4); v += __shfl_xor(v, 8);
            if (l == 0) out[b] = v + bfc0;
        }

        if (tc + 3 < chunk) {
            asm volatile("s_waitcnt lgkmcnt(0)" ::: "memory");  // buf reads done
            DMA(tc + 3);
        }
    }
#undef DMA
}

// ---------------------------------------------------------------------------
extern "C" void kernel_launch(void* const* d_in, const int* in_sizes, int n_in,
                              void* d_out, int out_size, void* d_ws, size_t ws_size,
                              hipStream_t stream) {
    const float* x_m = (const float*)d_in[0];
    const float* x_a = (const float*)d_in[1];
    const float* Wj  = (const float*)d_in[2];
    const float* bj  = (const float*)d_in[3];
    const float* Wr  = (const float*)d_in[4];
    const float* br  = (const float*)d_in[5];
    const float* Wo  = (const float*)d_in[6];
    const float* bo  = (const float*)d_in[7];
    const float* Wfc = (const float*)d_in[8];
    const float* bfc = (const float*)d_in[9];
    float* out = (float*)d_out;
    unsigned char* ws = (unsigned char*)d_ws;

    // time-chunk 64: per-chunk G = 46MB (L3-resident); shrink if ws smaller
    int chunk = 64;
    while (chunk > 32 && OG + (size_t)B * chunk * ROWB > ws_size) chunk >>= 1;

    {   // bf16 conversion + bias concat
        const int total = 5184 * 32 + B * T * A + 5184;
        prep_kernel<<<(total + 255) / 256, 256, 0, stream>>>(
            x_a, Wj, Wr, Wo, bj, br, bo, ws);
    }

    for (int t0 = 0; t0 < T; t0 += chunk) {
        gate_kernel<<<(B * chunk) / 32, 256, 0, stream>>>(ws, t0, chunk);
        scan_kernel<<<64, 64, 0, stream>>>(
            ws, x_m, Wfc, bfc, out, t0, chunk, t0 == 0 ? 1 : 0);
    }
}

// Round 13
// 270.338 us; speedup vs baseline: 1.7363x; 1.7363x over previous
//
#include <hip/hip_runtime.h>

// Problem constants (match reference setup_inputs)
constexpr int B = 64, T = 256, M = 16, A = 32, H = 64;
constexpr int ROWB = 11264;   // G row stride bytes: 10368 used (81g x 64gc x bf16) + pad = 11 x 1KB

typedef __attribute__((ext_vector_type(8))) short bf16x8;
typedef __attribute__((ext_vector_type(4))) float f32x4;

// ws layout
constexpr size_t OW = 0;                               // Wb  bf16 [5184][32]
constexpr size_t OX = 332800;                          // xb  bf16 [B*T][32]
constexpr size_t OB = OX + (size_t)B * T * A * 2;      // bias f32 [5184]
constexpr size_t OG = OB + 21504;                      // G rows (row-major bf16)

__device__ __forceinline__ float blo(unsigned u) { return __builtin_bit_cast(float, u << 16); }
__device__ __forceinline__ float bhi(unsigned u) { return __builtin_bit_cast(float, u & 0xffff0000u); }

template<int N> __device__ __forceinline__ void vmwait() {
    asm volatile("s_waitcnt vmcnt(%0)" :: "n"(N) : "memory");
}

// ---------------------------------------------------------------------------
// Prep: convert W (Wj|Wr|Wo) and x_a to bf16 (RNE); concat biases to f32.
// ---------------------------------------------------------------------------
__global__ __launch_bounds__(256) void prep_kernel(
    const float* __restrict__ x_a,
    const float* __restrict__ Wj, const float* __restrict__ Wr,
    const float* __restrict__ Wo,
    const float* __restrict__ bj, const float* __restrict__ br,
    const float* __restrict__ bo, unsigned char* ws)
{
    const int nW = 5184 * 32, nX = B * T * A, nB = 5184;
    int idx = blockIdx.x * 256 + threadIdx.x;
    if (idx >= nW + nX + nB) return;
    if (idx < nW + nX) {
        float v;
        ushort* dst;
        if (idx < nW) {
            int row = idx >> 5;
            v = (row < 1024) ? Wj[idx] : (row < 5120) ? Wr[idx - 1024 * 32] : Wo[idx - 5120 * 32];
            dst = (ushort*)(ws + OW) + idx;
        } else {
            v = x_a[idx - nW];
            dst = (ushort*)(ws + OX) + (idx - nW);
        }
        unsigned u = __builtin_bit_cast(unsigned, v);
        *dst = (ushort)((u + 0x7fffu + ((u >> 16) & 1u)) >> 16);   // RNE
    } else {
        int row = idx - nW - nX;
        float v = (row < 1024) ? bj[row] : (row < 5120) ? br[row - 1024] : bo[row - 5120];
        ((float*)(ws + OB))[row] = v;
    }
}

// ---------------------------------------------------------------------------
// Gate kernel (MFMA + LDS transpose; R11/R12-proven, byte-identical):
// block = 32 rows x all 81 groups. Run as ONE dispatch over all rows
// (512 blocks) -- per-CU store drain is the limiter and scales with
// resident blocks (R12 evidence: 128 blocks -> 645 GB/s, 512 -> ~2.7ns/row).
// ---------------------------------------------------------------------------
__global__ __launch_bounds__(256) void gate_kernel(
    unsigned char* ws, int t0, int chunk)
{
    const int tid = threadIdx.x, lane = tid & 63, wv = tid >> 6;
    const int l15 = lane & 15, l4 = lane >> 4;
    const ushort* Wb = (const ushort*)(ws + OW);
    const ushort* xb = (const ushort*)(ws + OX);
    const float*  bc = (const float*)(ws + OB);
    unsigned char* G = ws + OG;

    __shared__ ushort tr[4][32][152];

    const int r0 = blockIdx.x * 32;     // 32 consecutive rows, same batch (chunk % 32 == 0)
    const int bb = r0 / chunk, tcc = r0 % chunk;
    const long xrow0 = (long)bb * T + t0 + tcc;

    const bf16x8 bx0 = *(const bf16x8*)(xb + (xrow0 + l15) * 32 + l4 * 8);
    const bf16x8 bx1 = *(const bf16x8*)(xb + (xrow0 + 16 + l15) * 32 + l4 * 8);

    const int p0 = wv * 10;
    const int pend = p0 + ((wv == 3) ? 11 : 10);   // wave3: pairs 30..39 + (80,dup)
    const int rr = lane >> 4, c16 = lane & 15;
    const f32x4 zero = {0.f, 0.f, 0.f, 0.f};

    for (int p = p0; p < pend; ++p) {
        #pragma unroll
        for (int gl = 0; gl < 2; ++gl) {
            int g = 2 * p + gl;
            if (g > 80) g = 80;        // duplicate o-gate into the pad slot
            f32x4 d0[4], d1[4];
            #pragma unroll
            for (int ct = 0; ct < 4; ++ct) {
                const bf16x8 aW =
                    *(const bf16x8*)(Wb + (size_t)(g * 64 + ct * 16 + l15) * 32 + l4 * 8);
                d0[ct] = __builtin_amdgcn_mfma_f32_16x16x32_bf16(aW, bx0, zero, 0, 0, 0);
                d1[ct] = __builtin_amdgcn_mfma_f32_16x16x32_bf16(aW, bx1, zero, 0, 0, 0);
                const float4 bv = *(const float4*)(bc + g * 64 + ct * 16 + l4 * 4);
                d0[ct][0] += bv.x; d0[ct][1] += bv.y; d0[ct][2] += bv.z; d0[ct][3] += bv.w;
                d1[ct][0] += bv.x; d1[ct][1] += bv.y; d1[ct][2] += bv.z; d1[ct][3] += bv.w;
            }

            if (g < 80) {   // softmax over 64 gate-cols: lane-local 16 + shfl(16,32)
                float s0 = 0.f, s1 = 0.f;
                #pragma unroll
                for (int ct = 0; ct < 4; ++ct)
                    #pragma unroll
                    for (int j = 0; j < 4; ++j) {
                        d0[ct][j] = __expf(d0[ct][j]); s0 += d0[ct][j];
                        d1[ct][j] = __expf(d1[ct][j]); s1 += d1[ct][j];
                    }
                s0 += __shfl_xor(s0, 16); s0 += __shfl_xor(s0, 32);
                s1 += __shfl_xor(s1, 16); s1 += __shfl_xor(s1, 32);
                const float i0 = __fdividef(1.f, s0), i1 = __fdividef(1.f, s1);
                #pragma unroll
                for (int ct = 0; ct < 4; ++ct)
                    #pragma unroll
                    for (int j = 0; j < 4; ++j) { d0[ct][j] *= i0; d1[ct][j] *= i1; }
            } else {        // out-gate sigmoid
                #pragma unroll
                for (int ct = 0; ct < 4; ++ct)
                    #pragma unroll
                    for (int j = 0; j < 4; ++j) {
                        d0[ct][j] = __fdividef(1.f, 1.f + __expf(-d0[ct][j]));
                        d1[ct][j] = __fdividef(1.f, 1.f + __expf(-d1[ct][j]));
                    }
            }

            #pragma unroll
            for (int ct = 0; ct < 4; ++ct) {   // pack bf16, write LDS tiles
                unsigned lo0, hi0, lo1, hi1;
                asm volatile("v_cvt_pk_bf16_f32 %0, %1, %2" : "=v"(lo0) : "v"(d0[ct][0]), "v"(d0[ct][1]));
                asm volatile("v_cvt_pk_bf16_f32 %0, %1, %2" : "=v"(hi0) : "v"(d0[ct][2]), "v"(d0[ct][3]));
                asm volatile("v_cvt_pk_bf16_f32 %0, %1, %2" : "=v"(lo1) : "v"(d1[ct][0]), "v"(d1[ct][1]));
                asm volatile("v_cvt_pk_bf16_f32 %0, %1, %2" : "=v"(hi1) : "v"(d1[ct][2]), "v"(d1[ct][3]));
                *(uint2*)&tr[wv][l15][gl * 64 + ct * 16 + l4 * 4]      = make_uint2(lo0, hi0);
                *(uint2*)&tr[wv][16 + l15][gl * 64 + ct * 16 + l4 * 4] = make_uint2(lo1, hi1);
            }
        }

        // same-wave DS write->read ordering, then coalesced 256B-run stores
        asm volatile("s_waitcnt lgkmcnt(0)" ::: "memory");
        __builtin_amdgcn_sched_barrier(0);
        const size_t gbyte = (size_t)p * 256;
        #pragma unroll
        for (int i = 0; i < 8; ++i) {            // 2 tiles x 4 row-quads
            const int row = (i >> 2) * 16 + (i & 3) * 4 + rr;
            uint4 v = *(const uint4*)&tr[wv][row][c16 * 8];
            *(uint4*)(G + (size_t)(r0 + row) * ROWB + gbyte + c16 * 16) = v;
        }
        asm volatile("s_waitcnt lgkmcnt(0)" ::: "memory");  // reads done before next pass
        __builtin_amdgcn_sched_barrier(0);
    }
}

// ---------------------------------------------------------------------------
// Scan kernel v9: 4 WAVES per batch, 64-step window. Per step: wave w owns
// h-range w*16..w*16+15 (per lane: 4h x 4k MACs + 1 J m-row); shfl reduce
// across hsub; partials via LDS; wave 0 finishes (o, c write, pred). Raw
// barriers with lgkmcnt-only drains (vmcnt never drained mid-loop). DMA of
// 11x1KB split 3/3/3/2 across waves, 4-deep, per-wave counted vmcnt.
// ---------------------------------------------------------------------------
__global__ __launch_bounds__(256, 1) void scan_kernel(
    const unsigned char* __restrict__ ws,
    const float* __restrict__ x_m,
    const float* __restrict__ Wfc, const float* __restrict__ bfc,
    float* __restrict__ out, int t0, int toff, int chunkG, int first)
{
    const int b = blockIdx.x;
    const int tid = threadIdx.x, l = tid & 63, wv = tid >> 6;
    const int q = l & 15, hs = l >> 4;
    const unsigned char* G = ws + OG;

    __shared__ __align__(16) unsigned char buf[4][ROWB];   // 45KB, 4-deep
    __shared__ __align__(16) float part[4][64];
    __shared__ __align__(16) float c_sh[64];
    __shared__ __align__(16) float xm_s[64 * 16];

    float* cbase = out + B;   // c region: cbase[(b*T + t)*H + k]

    {   // stage x_m window (64 steps x 16) -- one float4 per thread
        const float4* src = (const float4*)(x_m + ((size_t)b * T + t0) * M);
        ((float4*)xm_s)[tid] = src[tid];
    }
    if (tid < 64)
        c_sh[tid] = first ? 0.f : cbase[((size_t)b * T + t0 - 1) * H + tid];
    const float wfck = Wfc[l];           // lane l <-> k (wave 0 uses it)
    const float bfc0 = bfc[0];

    const size_t rowbase = (size_t)b * chunkG + toff;
    asm volatile("s_waitcnt vmcnt(0) lgkmcnt(0)" ::: "memory");
    __builtin_amdgcn_s_barrier();

#define GLDS(SRC, DST)                                                          \
    __builtin_amdgcn_global_load_lds(                                           \
        (const __attribute__((address_space(1))) unsigned int*)(SRC),           \
        (__attribute__((address_space(3))) unsigned int*)(DST), 16, 0, 0)

#define DMA(tc_)                                                                \
    {                                                                           \
        const unsigned char* rp_ = G + (rowbase + (tc_)) * ROWB;                \
        unsigned char* lb_ = &buf[(tc_) & 3][0];                                \
        GLDS(rp_ + (size_t)wv * 1024 + l * 16,        lb_ + wv * 1024);         \
        GLDS(rp_ + (size_t)(wv + 4) * 1024 + l * 16,  lb_ + (wv + 4) * 1024);   \
        if (wv < 3)                                                             \
            GLDS(rp_ + (size_t)(wv + 8) * 1024 + l * 16, lb_ + (wv + 8) * 1024);\
    }

    DMA(0); DMA(1); DMA(2); DMA(3);

#define STEP(tc_, NB_)                                                          \
    {                                                                           \
        if (wv < 3) vmwait<3 * (NB_)>(); else vmwait<2 * (NB_)>();              \
        __builtin_amdgcn_s_barrier();                                           \
        __builtin_amdgcn_sched_barrier(0);                                      \
        const ushort* bp = (const ushort*)&buf[(tc_) & 3][0];                   \
        const float4 cc = *(const float4*)&c_sh[wv * 16 + hs * 4];              \
        const float xmv = xm_s[(tc_) * 16 + wv * 4 + hs];                       \
        float a0, a1, a2, a3;                                                   \
        {                                                                       \
            const uint2 u = *(const uint2*)(bp + (wv * 4 + hs) * 64 + q * 4);   \
            a0 = xmv * blo(u.x); a1 = xmv * bhi(u.x);                           \
            a2 = xmv * blo(u.y); a3 = xmv * bhi(u.y);                           \
        }                                                                       \
        {                                                                       \
            const int h0 = wv * 16 + hs * 4;                                    \
            const uint2 u0 = *(const uint2*)(bp + 1024 + (h0 + 0) * 64 + q * 4);\
            const uint2 u1 = *(const uint2*)(bp + 1024 + (h0 + 1) * 64 + q * 4);\
            const uint2 u2 = *(const uint2*)(bp + 1024 + (h0 + 2) * 64 + q * 4);\
            const uint2 u3 = *(const uint2*)(bp + 1024 + (h0 + 3) * 64 + q * 4);\
            a0 += cc.x * blo(u0.x); a1 += cc.x * bhi(u0.x);                     \
            a2 += cc.x * blo(u0.y); a3 += cc.x * bhi(u0.y);                     \
            a0 += cc.y * blo(u1.x); a1 += cc.y * bhi(u1.x);                     \
            a2 += cc.y * blo(u1.y); a3 += cc.y * bhi(u1.y);                     \
            a0 += cc.z * blo(u2.x); a1 += cc.z * bhi(u2.x);                     \
            a2 += cc.z * blo(u2.y); a3 += cc.z * bhi(u2.y);                     \
            a0 += cc.w * blo(u3.x); a1 += cc.w * bhi(u3.x);                     \
            a2 += cc.w * blo(u3.y); a3 += cc.w * bhi(u3.y);                     \
        }                                                                       \
        a0 += __shfl_xor(a0, 16); a1 += __shfl_xor(a1, 16);                     \
        a2 += __shfl_xor(a2, 16); a3 += __shfl_xor(a3, 16);                     \
        a0 += __shfl_xor(a0, 32); a1 += __shfl_xor(a1, 32);                     \
        a2 += __shfl_xor(a2, 32); a3 += __shfl_xor(a3, 32);                     \
        if (l < 16) *(float4*)&part[wv][q * 4] = make_float4(a0, a1, a2, a3);   \
        asm volatile("s_waitcnt lgkmcnt(0)" ::: "memory");                      \
        __builtin_amdgcn_s_barrier();                                           \
        if (wv == 0) {                                                          \
            const int k = l;                                                    \
            float m_new = part[0][k] + part[1][k] + part[2][k] + part[3][k];    \
            const unsigned uo = *(const unsigned*)(bp + 5120 + (k & ~1));       \
            const float o = (k & 1) ? bhi(uo) : blo(uo);                        \
            const float cn = (1.f - o) * m_new;                                 \
            c_sh[k] = cn;                                                       \
            cbase[((size_t)b * T + t0 + (tc_)) * H + k] = cn;                   \
            if (t0 + (tc_) == T - 1) {                                          \
                float v = o * m_new * wfck;                                     \
                v += __shfl_xor(v, 1);  v += __shfl_xor(v, 2);                  \
                v += __shfl_xor(v, 4);  v += __shfl_xor(v, 8);                  \
                v += __shfl_xor(v, 16); v += __shfl_xor(v, 32);                 \
                if (l == 0) out[b] = v + bfc0;                                  \
            }                                                                   \
            asm volatile("s_waitcnt lgkmcnt(0)" ::: "memory");                  \
        }                                                                       \
        __builtin_amdgcn_s_barrier();                                           \
        if ((tc_) + 4 < 64) DMA((tc_) + 4);                                     \
    }

    for (int tc = 0; tc <= 60; ++tc) STEP(tc, 3);
    STEP(61, 2);
    STEP(62, 1);
    STEP(63, 0);
#undef STEP
#undef DMA
#undef GLDS
}

// ---------------------------------------------------------------------------
extern "C" void kernel_launch(void* const* d_in, const int* in_sizes, int n_in,
                              void* d_out, int out_size, void* d_ws, size_t ws_size,
                              hipStream_t stream) {
    const float* x_m = (const float*)d_in[0];
    const float* x_a = (const float*)d_in[1];
    const float* Wj  = (const float*)d_in[2];
    const float* bj  = (const float*)d_in[3];
    const float* Wr  = (const float*)d_in[4];
    const float* br  = (const float*)d_in[5];
    const float* Wo  = (const float*)d_in[6];
    const float* bo  = (const float*)d_in[7];
    const float* Wfc = (const float*)d_in[8];
    const float* bfc = (const float*)d_in[9];
    float* out = (float*)d_out;
    unsigned char* ws = (unsigned char*)d_ws;

    // prefer one big G (185MB, proven to fit since R10); shrink if needed
    int chunkG = 256;
    while (chunkG > 64 && OG + (size_t)B * chunkG * ROWB > ws_size) chunkG >>= 1;

    {   // bf16 conversion + bias concat
        const int total = 5184 * 32 + B * T * A + 5184;
        prep_kernel<<<(total + 255) / 256, 256, 0, stream>>>(
            x_a, Wj, Wr, Wo, bj, br, bo, ws);
    }

    for (int c0 = 0; c0 < T; c0 += chunkG) {
        gate_kernel<<<(B * chunkG) / 32, 256, 0, stream>>>(ws, c0, chunkG);
        for (int t0 = c0; t0 < c0 + chunkG; t0 += 64)
            scan_kernel<<<64, 256, 0, stream>>>(
                ws, x_m, Wfc, bfc, out, t0, t0 - c0, chunkG, t0 == 0 ? 1 : 0);
    }
}

// Round 14
// 234.162 us; speedup vs baseline: 2.0046x; 1.1545x over previous
//
#include <hip/hip_runtime.h>

// Problem constants (match reference setup_inputs)
constexpr int B = 64, T = 256, M = 16, A = 32, H = 64;
constexpr int ROWB = 11264;   // G row stride bytes: 10368 used (81g x 64gc x bf16) + pad = 11 x 1KB

typedef __attribute__((ext_vector_type(8))) short bf16x8;
typedef __attribute__((ext_vector_type(4))) float f32x4;

// ws layout
constexpr size_t OW = 0;                               // Wb  bf16 [5184][32]
constexpr size_t OX = 332800;                          // xb  bf16 [B*T][32]
constexpr size_t OB = OX + (size_t)B * T * A * 2;      // bias f32 [5184]
constexpr size_t OG = OB + 21504;                      // G rows (row-major bf16)

__device__ __forceinline__ float blo(unsigned u) { return __builtin_bit_cast(float, u << 16); }
__device__ __forceinline__ float bhi(unsigned u) { return __builtin_bit_cast(float, u & 0xffff0000u); }

template<int N> __device__ __forceinline__ void vmwait() {
    asm volatile("s_waitcnt vmcnt(%0)" :: "n"(N) : "memory");
}

// ---------------------------------------------------------------------------
// Prep: convert W (Wj|Wr|Wo) and x_a to bf16 (RNE); concat biases to f32.
// ---------------------------------------------------------------------------
__global__ __launch_bounds__(256) void prep_kernel(
    const float* __restrict__ x_a,
    const float* __restrict__ Wj, const float* __restrict__ Wr,
    const float* __restrict__ Wo,
    const float* __restrict__ bj, const float* __restrict__ br,
    const float* __restrict__ bo, unsigned char* ws)
{
    const int nW = 5184 * 32, nX = B * T * A, nB = 5184;
    int idx = blockIdx.x * 256 + threadIdx.x;
    if (idx >= nW + nX + nB) return;
    if (idx < nW + nX) {
        float v;
        ushort* dst;
        if (idx < nW) {
            int row = idx >> 5;
            v = (row < 1024) ? Wj[idx] : (row < 5120) ? Wr[idx - 1024 * 32] : Wo[idx - 5120 * 32];
            dst = (ushort*)(ws + OW) + idx;
        } else {
            v = x_a[idx - nW];
            dst = (ushort*)(ws + OX) + (idx - nW);
        }
        unsigned u = __builtin_bit_cast(unsigned, v);
        *dst = (ushort)((u + 0x7fffu + ((u >> 16) & 1u)) >> 16);   // RNE
    } else {
        int row = idx - nW - nX;
        float v = (row < 1024) ? bj[row] : (row < 5120) ? br[row - 1024] : bo[row - 5120];
        ((float*)(ws + OB))[row] = v;
    }
}

// ---------------------------------------------------------------------------
// Gate kernel: 16 rows/block (grid = rows/16) to maximize co-resident
// blocks -> outstanding store streams (R12/R13 evidence: store drain scales
// with resident blocks). MFMA swapped GEMM; lane (t=l&15, gc=4*(l>>4)+reg);
// per group-pair LDS transpose tile [16][152] then 256B-run stores.
// ---------------------------------------------------------------------------
__global__ __launch_bounds__(256) void gate_kernel(
    unsigned char* ws, int t0, int chunk)
{
    const int tid = threadIdx.x, lane = tid & 63, wv = tid >> 6;
    const int l15 = lane & 15, l4 = lane >> 4;
    const ushort* Wb = (const ushort*)(ws + OW);
    const ushort* xb = (const ushort*)(ws + OX);
    const float*  bc = (const float*)(ws + OB);
    unsigned char* G = ws + OG;

    __shared__ ushort tr[4][16][152];   // 19.5KB

    const int r0 = blockIdx.x * 16;     // 16 consecutive rows, same batch (chunk % 16 == 0)
    const int bb = r0 / chunk, tcc = r0 % chunk;
    const long xrow0 = (long)bb * T + t0 + tcc;

    const bf16x8 bx = *(const bf16x8*)(xb + (xrow0 + l15) * 32 + l4 * 8);

    const int p0 = wv * 10;
    const int pend = p0 + ((wv == 3) ? 11 : 10);   // wave3: pairs 30..39 + (80,dup)
    const int rr = lane >> 4, c16 = lane & 15;
    const f32x4 zero = {0.f, 0.f, 0.f, 0.f};

    for (int p = p0; p < pend; ++p) {
        #pragma unroll
        for (int gl = 0; gl < 2; ++gl) {
            int g = 2 * p + gl;
            if (g > 80) g = 80;        // duplicate o-gate into the pad slot
            f32x4 d[4];
            #pragma unroll
            for (int ct = 0; ct < 4; ++ct) {
                const bf16x8 aW =
                    *(const bf16x8*)(Wb + (size_t)(g * 64 + ct * 16 + l15) * 32 + l4 * 8);
                d[ct] = __builtin_amdgcn_mfma_f32_16x16x32_bf16(aW, bx, zero, 0, 0, 0);
                const float4 bv = *(const float4*)(bc + g * 64 + ct * 16 + l4 * 4);
                d[ct][0] += bv.x; d[ct][1] += bv.y; d[ct][2] += bv.z; d[ct][3] += bv.w;
            }

            if (g < 80) {   // softmax over 64 gate-cols: lane-local 16 + shfl(16,32)
                float s = 0.f;
                #pragma unroll
                for (int ct = 0; ct < 4; ++ct)
                    #pragma unroll
                    for (int j = 0; j < 4; ++j) { d[ct][j] = __expf(d[ct][j]); s += d[ct][j]; }
                s += __shfl_xor(s, 16); s += __shfl_xor(s, 32);
                const float inv = __fdividef(1.f, s);
                #pragma unroll
                for (int ct = 0; ct < 4; ++ct)
                    #pragma unroll
                    for (int j = 0; j < 4; ++j) d[ct][j] *= inv;
            } else {        // out-gate sigmoid
                #pragma unroll
                for (int ct = 0; ct < 4; ++ct)
                    #pragma unroll
                    for (int j = 0; j < 4; ++j)
                        d[ct][j] = __fdividef(1.f, 1.f + __expf(-d[ct][j]));
            }

            #pragma unroll
            for (int ct = 0; ct < 4; ++ct) {   // pack bf16, write LDS tile
                unsigned lo, hi;
                asm volatile("v_cvt_pk_bf16_f32 %0, %1, %2" : "=v"(lo) : "v"(d[ct][0]), "v"(d[ct][1]));
                asm volatile("v_cvt_pk_bf16_f32 %0, %1, %2" : "=v"(hi) : "v"(d[ct][2]), "v"(d[ct][3]));
                *(uint2*)&tr[wv][l15][gl * 64 + ct * 16 + l4 * 4] = make_uint2(lo, hi);
            }
        }

        // same-wave DS write->read ordering, then coalesced 256B-run stores
        asm volatile("s_waitcnt lgkmcnt(0)" ::: "memory");
        __builtin_amdgcn_sched_barrier(0);
        const size_t gbyte = (size_t)p * 256;
        #pragma unroll
        for (int i = 0; i < 4; ++i) {            // 4 row-quads
            const int row = i * 4 + rr;
            uint4 v = *(const uint4*)&tr[wv][row][c16 * 8];
            *(uint4*)(G + (size_t)(r0 + row) * ROWB + gbyte + c16 * 16) = v;
        }
        asm volatile("s_waitcnt lgkmcnt(0)" ::: "memory");  // reads done before reuse
        __builtin_amdgcn_sched_barrier(0);
    }
}

// ---------------------------------------------------------------------------
// Scan kernel v10: 4 waves/batch, ONE dispatch for the whole window
// (up to 256 steps). 2 barriers/step; finish computed redundantly by ALL
// waves (no serial wave0 section); c_sh written redundantly (same values).
// 4-deep contiguous DMA (11x1KB/step, split 3/3/3/2 across waves) with
// per-wave counted vmcnt, never drained mid-loop.
// ---------------------------------------------------------------------------
__global__ __launch_bounds__(256, 1) void scan_kernel(
    const unsigned char* __restrict__ ws,
    const float* __restrict__ x_m,
    const float* __restrict__ Wfc, const float* __restrict__ bfc,
    float* __restrict__ out, int t0, int nsteps, int first)
{
    const int b = blockIdx.x;
    const int tid = threadIdx.x, l = tid & 63, wv = tid >> 6;
    const int q = l & 15, hs = l >> 4;
    const unsigned char* G = ws + OG;

    __shared__ __align__(16) unsigned char buf[4][ROWB];   // 45KB
    __shared__ __align__(16) float part[4][64];
    __shared__ __align__(16) float c_sh[64];
    __shared__ __align__(16) float xm_s[4096];             // nsteps<=256

    float* cbase = out + B;   // c region: cbase[(b*T + t)*H + k]

    {   // stage x_m window
        const float4* src = (const float4*)(x_m + ((size_t)b * T + t0) * M);
        float4* dst = (float4*)xm_s;
        for (int i = tid; i < nsteps * 4; i += 256) dst[i] = src[i];
    }
    if (tid < 64)
        c_sh[tid] = first ? 0.f : cbase[((size_t)b * T + t0 - 1) * H + tid];
    const float wfck = Wfc[l];
    const float bfc0 = bfc[0];

    const size_t rowbase = (size_t)b * nsteps;
    asm volatile("s_waitcnt vmcnt(0) lgkmcnt(0)" ::: "memory");
    __builtin_amdgcn_s_barrier();

#define GLDS(SRC, DST)                                                          \
    __builtin_amdgcn_global_load_lds(                                           \
        (const __attribute__((address_space(1))) unsigned int*)(SRC),           \
        (__attribute__((address_space(3))) unsigned int*)(DST), 16, 0, 0)

#define DMA(tc_)                                                                \
    {                                                                           \
        const unsigned char* rp_ = G + (rowbase + (tc_)) * ROWB;                \
        unsigned char* lb_ = &buf[(tc_) & 3][0];                                \
        GLDS(rp_ + (size_t)wv * 1024 + l * 16,        lb_ + wv * 1024);         \
        GLDS(rp_ + (size_t)(wv + 4) * 1024 + l * 16,  lb_ + (wv + 4) * 1024);   \
        if (wv < 3)                                                             \
            GLDS(rp_ + (size_t)(wv + 8) * 1024 + l * 16, lb_ + (wv + 8) * 1024);\
    }

    DMA(0); DMA(1); DMA(2); DMA(3);

    for (int tc = 0; tc < nsteps; ++tc) {
        const int rem = nsteps - 1 - tc;   // future batches beyond current
        if (wv < 3) {
            if (rem >= 3) vmwait<9>(); else if (rem == 2) vmwait<6>();
            else if (rem == 1) vmwait<3>(); else vmwait<0>();
        } else {
            if (rem >= 3) vmwait<6>(); else if (rem == 2) vmwait<4>();
            else if (rem == 1) vmwait<2>(); else vmwait<0>();
        }
        asm volatile("s_waitcnt lgkmcnt(0)" ::: "memory");
        __builtin_amdgcn_s_barrier();
        __builtin_amdgcn_sched_barrier(0);

        const ushort* bp = (const ushort*)&buf[tc & 3][0];
        const float4 cc = *(const float4*)&c_sh[wv * 16 + hs * 4];
        const float xmv = xm_s[tc * 16 + wv * 4 + hs];

        float a0, a1, a2, a3;
        {   // J: m = wv*4+hs
            const uint2 u = *(const uint2*)(bp + (wv * 4 + hs) * 64 + q * 4);
            a0 = xmv * blo(u.x); a1 = xmv * bhi(u.x);
            a2 = xmv * blo(u.y); a3 = xmv * bhi(u.y);
        }
        {   // R: h = wv*16 + hs*4 + 0..3
            const int h0 = wv * 16 + hs * 4;
            const uint2 u0 = *(const uint2*)(bp + 1024 + (h0 + 0) * 64 + q * 4);
            const uint2 u1 = *(const uint2*)(bp + 1024 + (h0 + 1) * 64 + q * 4);
            const uint2 u2 = *(const uint2*)(bp + 1024 + (h0 + 2) * 64 + q * 4);
            const uint2 u3 = *(const uint2*)(bp + 1024 + (h0 + 3) * 64 + q * 4);
            a0 += cc.x * blo(u0.x); a1 += cc.x * bhi(u0.x);
            a2 += cc.x * blo(u0.y); a3 += cc.x * bhi(u0.y);
            a0 += cc.y * blo(u1.x); a1 += cc.y * bhi(u1.x);
            a2 += cc.y * blo(u1.y); a3 += cc.y * bhi(u1.y);
            a0 += cc.z * blo(u2.x); a1 += cc.z * bhi(u2.x);
            a2 += cc.z * blo(u2.y); a3 += cc.z * bhi(u2.y);
            a0 += cc.w * blo(u3.x); a1 += cc.w * bhi(u3.x);
            a2 += cc.w * blo(u3.y); a3 += cc.w * bhi(u3.y);
        }
        a0 += __shfl_xor(a0, 16); a1 += __shfl_xor(a1, 16);
        a2 += __shfl_xor(a2, 16); a3 += __shfl_xor(a3, 16);
        a0 += __shfl_xor(a0, 32); a1 += __shfl_xor(a1, 32);
        a2 += __shfl_xor(a2, 32); a3 += __shfl_xor(a3, 32);
        if (l < 16) *(float4*)&part[wv][q * 4] = make_float4(a0, a1, a2, a3);
        asm volatile("s_waitcnt lgkmcnt(0)" ::: "memory");
        __builtin_amdgcn_s_barrier();
        __builtin_amdgcn_sched_barrier(0);

        // finish: ALL waves compute k = l redundantly (no serial section)
        const float m_new = part[0][l] + part[1][l] + part[2][l] + part[3][l];
        const float o = __builtin_bit_cast(float, (unsigned)bp[5120 + l] << 16);
        const float cn = (1.f - o) * m_new;
        c_sh[l] = cn;                         // redundant same-value writes
        if (wv == 0)
            cbase[((size_t)b * T + t0 + tc) * H + l] = cn;
        if (wv == 0 && t0 + tc == T - 1) {    // fused fc on last timestep
            float v = o * m_new * wfck;
            v += __shfl_xor(v, 1);  v += __shfl_xor(v, 2);
            v += __shfl_xor(v, 4);  v += __shfl_xor(v, 8);
            v += __shfl_xor(v, 16); v += __shfl_xor(v, 32);
            if (l == 0) out[b] = v + bfc0;
        }

        if (tc + 4 < nsteps) DMA(tc + 4);
    }
#undef DMA
#undef GLDS
}

// ---------------------------------------------------------------------------
extern "C" void kernel_launch(void* const* d_in, const int* in_sizes, int n_in,
                              void* d_out, int out_size, void* d_ws, size_t ws_size,
                              hipStream_t stream) {
    const float* x_m = (const float*)d_in[0];
    const float* x_a = (const float*)d_in[1];
    const float* Wj  = (const float*)d_in[2];
    const float* bj  = (const float*)d_in[3];
    const float* Wr  = (const float*)d_in[4];
    const float* br  = (const float*)d_in[5];
    const float* Wo  = (const float*)d_in[6];
    const float* bo  = (const float*)d_in[7];
    const float* Wfc = (const float*)d_in[8];
    const float* bfc = (const float*)d_in[9];
    float* out = (float*)d_out;
    unsigned char* ws = (unsigned char*)d_ws;

    // prefer one full-T G (185MB; proven to fit since R10); shrink if needed
    int chunkG = 256;
    while (chunkG > 64 && OG + (size_t)B * chunkG * ROWB > ws_size) chunkG >>= 1;

    {   // bf16 conversion + bias concat
        const int total = 5184 * 32 + B * T * A + 5184;
        prep_kernel<<<(total + 255) / 256, 256, 0, stream>>>(
            x_a, Wj, Wr, Wo, bj, br, bo, ws);
    }

    for (int c0 = 0; c0 < T; c0 += chunkG) {
        gate_kernel<<<(B * chunkG) / 16, 256, 0, stream>>>(ws, c0, chunkG);
        scan_kernel<<<64, 256, 0, stream>>>(
            ws, x_m, Wfc, bfc, out, c0, chunkG, c0 == 0 ? 1 : 0);
    }
}

// Round 17
// 205.587 us; speedup vs baseline: 2.2832x; 1.1390x over previous
//
#include <hip/hip_runtime.h>

// Problem constants (match reference setup_inputs)
constexpr int B = 64, T = 256, M = 16, A = 32, H = 64;
constexpr int ROWB = 11264;   // G row: 11 x 1KB octet granules

typedef __attribute__((ext_vector_type(8))) short bf16x8;
typedef __attribute__((ext_vector_type(4))) float f32x4;
typedef _Float16 half2 __attribute__((ext_vector_type(2)));
typedef __fp16 fp16x2 __attribute__((ext_vector_type(2)));   // cvt_pkrtz return type

// ws layout
constexpr size_t OW  = 0;              // W  bf16 [5184][32]
constexpr size_t OX  = 332800;         // x_a bf16 [B*T][32]
constexpr size_t OB  = 1381376;        // bias f32 [5184]
constexpr size_t OXM = 1402880;        // x_m f16 [B*T][16]
constexpr size_t OG  = 1927168;        // G rows

// G row layout (f16, octet granules of 1KB):
//   [0,1KB):  J-oct0: granule k holds (J[m=0..7][k]) as 8 f16
//   [1,2KB):  J-oct1: m=8..15
//   [2+ro KB): R-oct ro: granule k holds (R[h=ro*8..ro*8+7][k])
//   [10,11KB): o-oct: granule k holds o[k] x8 (dup)

template<int N> __device__ __forceinline__ void vmwait() {
    asm volatile("s_waitcnt vmcnt(%0)" :: "n"(N) : "memory");
}
__device__ __forceinline__ float dot2(unsigned a, unsigned b, float c) {
    return __builtin_amdgcn_fdot2(__builtin_bit_cast(half2, a),
                                  __builtin_bit_cast(half2, b), c, false);
}
__device__ __forceinline__ unsigned pkrtz(float a, float b) {
    fp16x2 pk = __builtin_amdgcn_cvt_pkrtz(a, b);
    return __builtin_bit_cast(unsigned, pk);
}

// ---------------------------------------------------------------------------
// Prep: W,x_a -> bf16 (RNE); x_m -> f16; biases -> f32 concat.
// ---------------------------------------------------------------------------
__global__ __launch_bounds__(256) void prep_kernel(
    const float* __restrict__ x_a, const float* __restrict__ x_m,
    const float* __restrict__ Wj, const float* __restrict__ Wr,
    const float* __restrict__ Wo,
    const float* __restrict__ bj, const float* __restrict__ br,
    const float* __restrict__ bo, unsigned char* ws)
{
    const int nW = 5184 * 32, nX = B * T * A, nXM = B * T * M, nB = 5184;
    int idx = blockIdx.x * 256 + threadIdx.x;
    if (idx >= nW + nX + nXM + nB) return;
    if (idx < nW + nX) {
        float v; ushort* dst;
        if (idx < nW) {
            int row = idx >> 5;
            v = (row < 1024) ? Wj[idx] : (row < 5120) ? Wr[idx - 1024 * 32] : Wo[idx - 5120 * 32];
            dst = (ushort*)(ws + OW) + idx;
        } else {
            v = x_a[idx - nW];
            dst = (ushort*)(ws + OX) + (idx - nW);
        }
        unsigned u = __builtin_bit_cast(unsigned, v);
        *dst = (ushort)((u + 0x7fffu + ((u >> 16) & 1u)) >> 16);   // RNE
    } else if (idx < nW + nX + nXM) {
        int j = idx - nW - nX;
        ((_Float16*)(ws + OXM))[j] = (_Float16)x_m[j];
    } else {
        int row = idx - nW - nX - nXM;
        float v = (row < 1024) ? bj[row] : (row < 5120) ? br[row - 1024] : bo[row - 5120];
        ((float*)(ws + OB))[row] = v;
    }
}

// ---------------------------------------------------------------------------
// Gate kernel: 128 threads (2 waves), 16 rows/block, grid = B*T/16 = 1024.
// Wave wv handles octets {2*oi + wv}. Per octet: 8 groups (g = oct*8+gi),
// MFMA swapped GEMM (lane: t=l&15, gc=ct*16+(l>>4)*4+j), softmax/sigmoid,
// f16-pack pairs into per-wave tile [16t][64k][8h]; store 1KB runs.
// ---------------------------------------------------------------------------
__global__ __launch_bounds__(128) void gate_kernel(unsigned char* ws)
{
    const int tid = threadIdx.x, l = tid & 63, wv = tid >> 6;
    const int l15 = l & 15, l4 = l >> 4;
    const ushort* Wb = (const ushort*)(ws + OW);
    const ushort* xb = (const ushort*)(ws + OX);
    const float*  bc = (const float*)(ws + OB);
    unsigned char* G = ws + OG;

    __shared__ __align__(16) unsigned char tile[2 * 16 * 1040];  // 32.5KB
    unsigned char* wtile = tile + wv * 16 * 1040;

    const int r0 = blockIdx.x * 16;                 // global row = b*T + t
    const bf16x8 bx = *(const bf16x8*)(xb + (size_t)(r0 + l15) * 32 + l4 * 8);
    const f32x4 zero = {0.f, 0.f, 0.f, 0.f};

    const int no = (wv == 0) ? 6 : 5;
    for (int oi = 0; oi < no; ++oi) {
        const int oct = oi * 2 + wv;

        if (oct < 10) {
            f32x4 s[4];
            #pragma unroll
            for (int gi = 0; gi < 8; ++gi) {
                const int g = oct * 8 + gi;
                f32x4 d[4];
                #pragma unroll
                for (int ct = 0; ct < 4; ++ct) {
                    const bf16x8 aW = *(const bf16x8*)(
                        Wb + (size_t)(g * 64 + ct * 16 + l15) * 32 + l4 * 8);
                    d[ct] = __builtin_amdgcn_mfma_f32_16x16x32_bf16(aW, bx, zero, 0, 0, 0);
                    const float4 bv = *(const float4*)(bc + g * 64 + ct * 16 + l4 * 4);
                    d[ct][0] += bv.x; d[ct][1] += bv.y; d[ct][2] += bv.z; d[ct][3] += bv.w;
                }
                {   // softmax over 64 gc: 16 lane-local + shfl(16,32)
                    float sm = 0.f;
                    #pragma unroll
                    for (int ct = 0; ct < 4; ++ct)
                        #pragma unroll
                        for (int j = 0; j < 4; ++j) { d[ct][j] = __expf(d[ct][j]); sm += d[ct][j]; }
                    sm += __shfl_xor(sm, 16); sm += __shfl_xor(sm, 32);
                    const float inv = __fdividef(1.f, sm);
                    #pragma unroll
                    for (int ct = 0; ct < 4; ++ct)
                        #pragma unroll
                        for (int j = 0; j < 4; ++j) d[ct][j] *= inv;
                }
                if (gi & 1) {
                    const int p = gi >> 1;
                    #pragma unroll
                    for (int ct = 0; ct < 4; ++ct)
                        #pragma unroll
                        for (int j = 0; j < 4; ++j) {
                            const int gc = ct * 16 + l4 * 4 + j;
                            *(unsigned*)(wtile + l15 * 1040 + gc * 16 + p * 4) =
                                pkrtz(s[ct][j], d[ct][j]);
                        }
                } else {
                    #pragma unroll
                    for (int ct = 0; ct < 4; ++ct) s[ct] = d[ct];
                }
            }
        } else {    // o-octet: g=80 sigmoid once, duplicate x8
            f32x4 d[4];
            #pragma unroll
            for (int ct = 0; ct < 4; ++ct) {
                const bf16x8 aW = *(const bf16x8*)(
                    Wb + (size_t)(80 * 64 + ct * 16 + l15) * 32 + l4 * 8);
                d[ct] = __builtin_amdgcn_mfma_f32_16x16x32_bf16(aW, bx, zero, 0, 0, 0);
                const float4 bv = *(const float4*)(bc + 80 * 64 + ct * 16 + l4 * 4);
                d[ct][0] += bv.x; d[ct][1] += bv.y; d[ct][2] += bv.z; d[ct][3] += bv.w;
                #pragma unroll
                for (int j = 0; j < 4; ++j)
                    d[ct][j] = __fdividef(1.f, 1.f + __expf(-d[ct][j]));
            }
            #pragma unroll
            for (int ct = 0; ct < 4; ++ct)
                #pragma unroll
                for (int j = 0; j < 4; ++j) {
                    const int gc = ct * 16 + l4 * 4 + j;
                    unsigned u = pkrtz(d[ct][j], d[ct][j]);
                    unsigned char* base = wtile + l15 * 1040 + gc * 16;
                    *(unsigned*)(base + 0)  = u; *(unsigned*)(base + 4)  = u;
                    *(unsigned*)(base + 8)  = u; *(unsigned*)(base + 12) = u;
                }
        }

        // store phase: per t, 64 lanes x 16B = one contiguous 1KB granule run
        asm volatile("s_waitcnt lgkmcnt(0)" ::: "memory");
        __builtin_amdgcn_sched_barrier(0);
        #pragma unroll
        for (int t = 0; t < 16; ++t) {
            uint4 v = *(const uint4*)(wtile + t * 1040 + l * 16);
            *(uint4*)(G + (size_t)(r0 + t) * ROWB + oct * 1024 + l * 16) = v;
        }
        asm volatile("s_waitcnt lgkmcnt(0)" ::: "memory");
        __builtin_amdgcn_sched_barrier(0);
    }
}

// ---------------------------------------------------------------------------
// Scan kernel: 64 blocks x 1 wave, lane = k. Per step: 11 per-lane b128
// reads (J-octs, R-octs, o) + 8 uniform b128 (packed-f16 c pairs) + 40
// v_dot2_f32_f16 on 4 chains. No shuffles, no barriers. Depth-6 DMA with
// exact counted vmcnt (never drained mid-loop).
// ---------------------------------------------------------------------------
__global__ __launch_bounds__(64, 1) void scan_kernel(
    const unsigned char* __restrict__ ws,
    const float* __restrict__ Wfc, const float* __restrict__ bfc,
    float* __restrict__ out)
{
    const int b = blockIdx.x, l = threadIdx.x;
    const unsigned char* G = ws + OG;

    __shared__ __align__(16) unsigned char buf[6][ROWB];   // 66KB
    __shared__ __align__(16) unsigned xs[2048];            // x_m f16 pairs, 8KB
    __shared__ __align__(16) unsigned c_pk[32];            // c packed f16

    float* cbase = out + B;   // c region: cbase[(b*T + t)*H + k]

    {   // stage x_m f16 window (8KB)
        uint4* xd = (uint4*)xs;
        const uint4* xsrc = (const uint4*)(ws + OXM + (size_t)b * T * 32);
        #pragma unroll
        for (int i = 0; i < 8; ++i) xd[l + i * 64] = xsrc[l + i * 64];
    }
    if (l < 32) c_pk[l] = 0;                   // c0 = 0
    const float wfck = Wfc[l];
    const float bfc0 = bfc[0];
    asm volatile("s_waitcnt vmcnt(0) lgkmcnt(0)" ::: "memory");

#define DMA(tc_, bi_)                                                           \
    {                                                                           \
        const unsigned char* rp_ = G + (size_t)(b * T + (tc_)) * ROWB;          \
        unsigned char* lb_ = &buf[bi_][0];                                      \
        _Pragma("unroll")                                                       \
        for (int i_ = 0; i_ < 11; ++i_)                                         \
            __builtin_amdgcn_global_load_lds(                                   \
                (const __attribute__((address_space(1))) unsigned int*)         \
                    (rp_ + i_ * 1024 + l * 16),                                 \
                (__attribute__((address_space(3))) unsigned int*)               \
                    (lb_ + i_ * 1024), 16, 0, 0);                               \
    }

    DMA(0, 0); DMA(1, 1); DMA(2, 2); DMA(3, 3); DMA(4, 4); DMA(5, 5);

    const uint4* cq = (const uint4*)c_pk;
    const uint4* xq = (const uint4*)xs;
    int bi = 0;

    for (int tc = 0; tc < T; ++tc) {
        // exact counted waits: N = 11*min(5,rem) + (#stores issued after batch tc)
        const int rem = (T - 1) - tc;
        if (tc >= 5) {
            if      (rem >= 5) vmwait<60>();
            else if (rem == 4) vmwait<49>();
            else if (rem == 3) vmwait<38>();
            else if (rem == 2) vmwait<27>();
            else if (rem == 1) vmwait<16>();
            else               vmwait<5>();
        } else {
            if      (tc == 0) vmwait<55>();
            else if (tc == 1) vmwait<56>();
            else if (tc == 2) vmwait<57>();
            else if (tc == 3) vmwait<58>();
            else              vmwait<59>();
        }
        __builtin_amdgcn_sched_barrier(0);

        const unsigned char* bp = &buf[bi][0];

        const uint4 J0 = *(const uint4*)(bp + l * 16);
        const uint4 J1 = *(const uint4*)(bp + 1024 + l * 16);
        const uint4 R0 = *(const uint4*)(bp + 2048 + l * 16);
        const uint4 R1 = *(const uint4*)(bp + 3072 + l * 16);
        const uint4 R2 = *(const uint4*)(bp + 4096 + l * 16);
        const uint4 R3 = *(const uint4*)(bp + 5120 + l * 16);
        const uint4 R4 = *(const uint4*)(bp + 6144 + l * 16);
        const uint4 R5 = *(const uint4*)(bp + 7168 + l * 16);
        const uint4 R6 = *(const uint4*)(bp + 8192 + l * 16);
        const uint4 R7 = *(const uint4*)(bp + 9216 + l * 16);
        const float o = (float)*(const _Float16*)(bp + 10240 + l * 16);

        const uint4 X0 = xq[tc * 2], X1 = xq[tc * 2 + 1];      // uniform
        const uint4 C0 = cq[0], C1 = cq[1], C2 = cq[2], C3 = cq[3];
        const uint4 C4 = cq[4], C5 = cq[5], C6 = cq[6], C7 = cq[7];

        float a0 = 0.f, a1 = 0.f, a2 = 0.f, a3 = 0.f;
        a0 = dot2(X0.x, J0.x, a0); a0 = dot2(X0.y, J0.y, a0);
        a0 = dot2(X0.z, J0.z, a0); a0 = dot2(X0.w, J0.w, a0);
        a1 = dot2(X1.x, J1.x, a1); a1 = dot2(X1.y, J1.y, a1);
        a1 = dot2(X1.z, J1.z, a1); a1 = dot2(X1.w, J1.w, a1);
        a0 = dot2(C0.x, R0.x, a0); a0 = dot2(C0.y, R0.y, a0);
        a0 = dot2(C0.z, R0.z, a0); a0 = dot2(C0.w, R0.w, a0);
        a0 = dot2(C1.x, R1.x, a0); a0 = dot2(C1.y, R1.y, a0);
        a0 = dot2(C1.z, R1.z, a0); a0 = dot2(C1.w, R1.w, a0);
        a1 = dot2(C2.x, R2.x, a1); a1 = dot2(C2.y, R2.y, a1);
        a1 = dot2(C2.z, R2.z, a1); a1 = dot2(C2.w, R2.w, a1);
        a1 = dot2(C3.x, R3.x, a1); a1 = dot2(C3.y, R3.y, a1);
        a1 = dot2(C3.z, R3.z, a1); a1 = dot2(C3.w, R3.w, a1);
        a2 = dot2(C4.x, R4.x, a2); a2 = dot2(C4.y, R4.y, a2);
        a2 = dot2(C4.z, R4.z, a2); a2 = dot2(C4.w, R4.w, a2);
        a2 = dot2(C5.x, R5.x, a2); a2 = dot2(C5.y, R5.y, a2);
        a2 = dot2(C5.z, R5.z, a2); a2 = dot2(C5.w, R5.w, a2);
        a3 = dot2(C6.x, R6.x, a3); a3 = dot2(C6.y, R6.y, a3);
        a3 = dot2(C6.z, R6.z, a3); a3 = dot2(C6.w, R6.w, a3);
        a3 = dot2(C7.x, R7.x, a3); a3 = dot2(C7.y, R7.y, a3);
        a3 = dot2(C7.z, R7.z, a3); a3 = dot2(C7.w, R7.w, a3);

        const float m_new = (a0 + a1) + (a2 + a3);
        const float cn = (1.f - o) * m_new;

        cbase[((size_t)b * T + tc) * H + l] = cn;      // 256B coalesced
        ((_Float16*)c_pk)[l] = (_Float16)cn;           // pack for next step

        if (tc == T - 1) {                              // fused fc
            float v = o * m_new * wfck;
            v += __shfl_xor(v, 1);  v += __shfl_xor(v, 2);
            v += __shfl_xor(v, 4);  v += __shfl_xor(v, 8);
            v += __shfl_xor(v, 16); v += __shfl_xor(v, 32);
            if (l == 0) out[b] = v + bfc0;
        }

        asm volatile("s_waitcnt lgkmcnt(0)" ::: "memory");  // c_pk visible; buf reads done
        __builtin_amdgcn_sched_barrier(0);

        if (tc + 6 < T) DMA(tc + 6, bi);
        bi = (bi == 5) ? 0 : bi + 1;
    }
#undef DMA
}

// ---------------------------------------------------------------------------
extern "C" void kernel_launch(void* const* d_in, const int* in_sizes, int n_in,
                              void* d_out, int out_size, void* d_ws, size_t ws_size,
                              hipStream_t stream) {
    const float* x_m = (const float*)d_in[0];
    const float* x_a = (const float*)d_in[1];
    const float* Wj  = (const float*)d_in[2];
    const float* bj  = (const float*)d_in[3];
    const float* Wr  = (const float*)d_in[4];
    const float* br  = (const float*)d_in[5];
    const float* Wo  = (const float*)d_in[6];
    const float* bo  = (const float*)d_in[7];
    const float* Wfc = (const float*)d_in[8];
    const float* bfc = (const float*)d_in[9];
    float* out = (float*)d_out;
    unsigned char* ws = (unsigned char*)d_ws;

    {   // conversions: W,x_a->bf16; x_m->f16; bias concat
        const int total = 5184 * 32 + B * T * A + B * T * M + 5184;
        prep_kernel<<<(total + 255) / 256, 256, 0, stream>>>(
            x_a, x_m, Wj, Wr, Wo, bj, br, bo, ws);
    }
    gate_kernel<<<(B * T) / 16, 128, 0, stream>>>(ws);
    scan_kernel<<<64, 64, 0, stream>>>(ws, Wfc, bfc, out);
}

// Round 18
// 117.209 us; speedup vs baseline: 4.0048x; 1.7540x over previous
//
#include <hip/hip_runtime.h>

// Problem constants (match reference setup_inputs)
constexpr int B = 64, T = 256, M = 16, A = 32, H = 64;
constexpr int ROWB = 11264;   // G row: 11 x 1KB octet granules
constexpr int S = 32;         // time-block length
constexpr int NBLK = T / S;   // 8

typedef __attribute__((ext_vector_type(8))) short bf16x8;
typedef __attribute__((ext_vector_type(4))) float f32x4;
typedef _Float16 half2 __attribute__((ext_vector_type(2)));
typedef __fp16 fp16x2 __attribute__((ext_vector_type(2)));
typedef _Float16 f16x8 __attribute__((ext_vector_type(8)));

// ws layout
constexpr size_t OW  = 0;              // W  bf16 [5184][32]
constexpr size_t OX  = 332800;         // x_a bf16 [B*T][32]
constexpr size_t OB  = 1381376;        // bias f32 [5184]
constexpr size_t OXM = 1402880;        // x_m f16 [B*T][16]
constexpr size_t OG  = 1927168;        // G rows (f16 octet granules)
constexpr size_t OP  = OG + (size_t)B * T * ROWB;      // P~ f16 [512][64][72]
constexpr size_t OC  = OP + (size_t)B * NBLK * 64 * 144; // c_in f16 [512][64]

template<int N> __device__ __forceinline__ void vmwait() {
    asm volatile("s_waitcnt vmcnt(%0)" :: "n"(N) : "memory");
}
__device__ __forceinline__ float dot2(unsigned a, unsigned b, float c) {
    return __builtin_amdgcn_fdot2(__builtin_bit_cast(half2, a),
                                  __builtin_bit_cast(half2, b), c, false);
}
__device__ __forceinline__ unsigned pkrtz(float a, float b) {
    fp16x2 pk = __builtin_amdgcn_cvt_pkrtz(a, b);
    return __builtin_bit_cast(unsigned, pk);
}
__device__ __forceinline__ float h2f(unsigned u) {
    return (float)__builtin_bit_cast(_Float16, (unsigned short)(u & 0xffffu));
}

// ---------------------------------------------------------------------------
// Prep: W,x_a -> bf16 (RNE); x_m -> f16; biases -> f32 concat.
// ---------------------------------------------------------------------------
__global__ __launch_bounds__(256) void prep_kernel(
    const float* __restrict__ x_a, const float* __restrict__ x_m,
    const float* __restrict__ Wj, const float* __restrict__ Wr,
    const float* __restrict__ Wo,
    const float* __restrict__ bj, const float* __restrict__ br,
    const float* __restrict__ bo, unsigned char* ws)
{
    const int nW = 5184 * 32, nX = B * T * A, nXM = B * T * M, nB = 5184;
    int idx = blockIdx.x * 256 + threadIdx.x;
    if (idx >= nW + nX + nXM + nB) return;
    if (idx < nW + nX) {
        float v; ushort* dst;
        if (idx < nW) {
            int row = idx >> 5;
            v = (row < 1024) ? Wj[idx] : (row < 5120) ? Wr[idx - 1024 * 32] : Wo[idx - 5120 * 32];
            dst = (ushort*)(ws + OW) + idx;
        } else {
            v = x_a[idx - nW];
            dst = (ushort*)(ws + OX) + (idx - nW);
        }
        unsigned u = __builtin_bit_cast(unsigned, v);
        *dst = (ushort)((u + 0x7fffu + ((u >> 16) & 1u)) >> 16);   // RNE
    } else if (idx < nW + nX + nXM) {
        int j = idx - nW - nX;
        ((_Float16*)(ws + OXM))[j] = (_Float16)x_m[j];
    } else {
        int row = idx - nW - nX - nXM;
        float v = (row < 1024) ? bj[row] : (row < 5120) ? br[row - 1024] : bo[row - 5120];
        ((float*)(ws + OB))[row] = v;
    }
}

// ---------------------------------------------------------------------------
// Gate kernel (R17-proven, unchanged): 2 waves, 16 rows/block, MFMA swapped
// GEMM, f16 pack into octet-granule G rows, 1KB-run stores.
// ---------------------------------------------------------------------------
__global__ __launch_bounds__(128) void gate_kernel(unsigned char* ws)
{
    const int tid = threadIdx.x, l = tid & 63, wv = tid >> 6;
    const int l15 = l & 15, l4 = l >> 4;
    const ushort* Wb = (const ushort*)(ws + OW);
    const ushort* xb = (const ushort*)(ws + OX);
    const float*  bc = (const float*)(ws + OB);
    unsigned char* G = ws + OG;

    __shared__ __align__(16) unsigned char tile[2 * 16 * 1040];
    unsigned char* wtile = tile + wv * 16 * 1040;

    const int r0 = blockIdx.x * 16;
    const bf16x8 bx = *(const bf16x8*)(xb + (size_t)(r0 + l15) * 32 + l4 * 8);
    const f32x4 zero = {0.f, 0.f, 0.f, 0.f};

    const int no = (wv == 0) ? 6 : 5;
    for (int oi = 0; oi < no; ++oi) {
        const int oct = oi * 2 + wv;

        if (oct < 10) {
            f32x4 s[4];
            #pragma unroll
            for (int gi = 0; gi < 8; ++gi) {
                const int g = oct * 8 + gi;
                f32x4 d[4];
                #pragma unroll
                for (int ct = 0; ct < 4; ++ct) {
                    const bf16x8 aW = *(const bf16x8*)(
                        Wb + (size_t)(g * 64 + ct * 16 + l15) * 32 + l4 * 8);
                    d[ct] = __builtin_amdgcn_mfma_f32_16x16x32_bf16(aW, bx, zero, 0, 0, 0);
                    const float4 bv = *(const float4*)(bc + g * 64 + ct * 16 + l4 * 4);
                    d[ct][0] += bv.x; d[ct][1] += bv.y; d[ct][2] += bv.z; d[ct][3] += bv.w;
                }
                {
                    float sm = 0.f;
                    #pragma unroll
                    for (int ct = 0; ct < 4; ++ct)
                        #pragma unroll
                        for (int j = 0; j < 4; ++j) { d[ct][j] = __expf(d[ct][j]); sm += d[ct][j]; }
                    sm += __shfl_xor(sm, 16); sm += __shfl_xor(sm, 32);
                    const float inv = __fdividef(1.f, sm);
                    #pragma unroll
                    for (int ct = 0; ct < 4; ++ct)
                        #pragma unroll
                        for (int j = 0; j < 4; ++j) d[ct][j] *= inv;
                }
                if (gi & 1) {
                    const int p = gi >> 1;
                    #pragma unroll
                    for (int ct = 0; ct < 4; ++ct)
                        #pragma unroll
                        for (int j = 0; j < 4; ++j) {
                            const int gc = ct * 16 + l4 * 4 + j;
                            *(unsigned*)(wtile + l15 * 1040 + gc * 16 + p * 4) =
                                pkrtz(s[ct][j], d[ct][j]);
                        }
                } else {
                    #pragma unroll
                    for (int ct = 0; ct < 4; ++ct) s[ct] = d[ct];
                }
            }
        } else {
            f32x4 d[4];
            #pragma unroll
            for (int ct = 0; ct < 4; ++ct) {
                const bf16x8 aW = *(const bf16x8*)(
                    Wb + (size_t)(80 * 64 + ct * 16 + l15) * 32 + l4 * 8);
                d[ct] = __builtin_amdgcn_mfma_f32_16x16x32_bf16(aW, bx, zero, 0, 0, 0);
                const float4 bv = *(const float4*)(bc + 80 * 64 + ct * 16 + l4 * 4);
                d[ct][0] += bv.x; d[ct][1] += bv.y; d[ct][2] += bv.z; d[ct][3] += bv.w;
                #pragma unroll
                for (int j = 0; j < 4; ++j)
                    d[ct][j] = __fdividef(1.f, 1.f + __expf(-d[ct][j]));
            }
            #pragma unroll
            for (int ct = 0; ct < 4; ++ct)
                #pragma unroll
                for (int j = 0; j < 4; ++j) {
                    const int gc = ct * 16 + l4 * 4 + j;
                    unsigned u = pkrtz(d[ct][j], d[ct][j]);
                    unsigned char* base = wtile + l15 * 1040 + gc * 16;
                    *(unsigned*)(base + 0)  = u; *(unsigned*)(base + 4)  = u;
                    *(unsigned*)(base + 8)  = u; *(unsigned*)(base + 12) = u;
                }
        }

        asm volatile("s_waitcnt lgkmcnt(0)" ::: "memory");
        __builtin_amdgcn_sched_barrier(0);
        #pragma unroll
        for (int t = 0; t < 16; ++t) {
            uint4 v = *(const uint4*)(wtile + t * 1040 + l * 16);
            *(uint4*)(G + (size_t)(r0 + t) * ROWB + oct * 1024 + l * 16) = v;
        }
        asm volatile("s_waitcnt lgkmcnt(0)" ::: "memory");
        __builtin_amdgcn_sched_barrier(0);
    }
}

// ---------------------------------------------------------------------------
// Compose: per (b,blk) chain P~ <- A_t P~ (+d on col 64), A_t = D_t R_t^T.
// 4 waves; wave w owns output rows w*16..+15. G's R-octet granules ARE the
// MFMA A-fragments of R^T (per-lane b128, no staging). P~ (64x80 f32 acc)
// round-trips through LDS as f16 granules each step (B-fragments).
// ---------------------------------------------------------------------------
__global__ __launch_bounds__(256, 2) void compose_kernel(unsigned char* ws)
{
    const int tid = threadIdx.x, l = tid & 63, wv = tid >> 6;
    const int l15 = l & 15, l4 = l >> 4;
    const unsigned char* G = ws + OG;

    __shared__ __align__(16) unsigned char P_lds[8 * 1296];  // hoct stride 1296 (81x16B)
    __shared__ __align__(16) float d_lds[64];
    __shared__ __align__(16) float dD_lds[64];
    __shared__ __align__(16) unsigned xs[256];               // 32 steps x 16 f16

    const int bb = blockIdx.x >> 3, blk = blockIdx.x & 7;
    const size_t row0 = (size_t)bb * T + blk * S;
    const uint4* xq = (const uint4*)xs;

    if (tid < 64)
        ((uint4*)xs)[tid] = ((const uint4*)(ws + OXM + row0 * 32))[tid];

    float acc[5][4];
    #pragma unroll
    for (int ct = 0; ct < 5; ++ct)
        #pragma unroll
        for (int j = 0; j < 4; ++j) {
            const int r = wv * 16 + l4 * 4 + j, c = ct * 16 + l15;
            acc[ct][j] = (r == c) ? 1.f : 0.f;
        }
    __syncthreads();

    // prefetch step-0 global loads
    uint4 A0n, A1n, J0n, J1n; unsigned on_ = 0;
    {
        const unsigned char* rp = G + row0 * ROWB;
        A0n = *(const uint4*)(rp + 2048 + l4 * 1024 + (wv * 16 + l15) * 16);
        A1n = *(const uint4*)(rp + 2048 + (4 + l4) * 1024 + (wv * 16 + l15) * 16);
        if (wv == 0) {
            J0n = *(const uint4*)(rp + l * 16);
            J1n = *(const uint4*)(rp + 1024 + l * 16);
            on_ = *(const ushort*)(rp + 10240 + l * 16);
        }
    }

    for (int tc = 0; tc < S; ++tc) {
        const uint4 A0 = A0n, A1 = A1n, J0 = J0n, J1 = J1n;
        const unsigned ou = on_;

        // write P_{tc-1} (acc) into P_lds as f16 h-octet granules
        #pragma unroll
        for (int ct = 0; ct < 5; ++ct) {
            const int hoct = wv * 2 + (l4 >> 1);
            *(uint2*)(P_lds + hoct * 1296 + (ct * 16 + l15) * 16 + (l4 & 1) * 8) =
                make_uint2(pkrtz(acc[ct][0], acc[ct][1]), pkrtz(acc[ct][2], acc[ct][3]));
        }
        if (wv == 0) {    // d = D*m_in, dD = 1-o (lane l = row)
            const uint4 X0 = xq[tc * 2], X1 = xq[tc * 2 + 1];
            float m = 0.f;
            m = dot2(X0.x, J0.x, m); m = dot2(X0.y, J0.y, m);
            m = dot2(X0.z, J0.z, m); m = dot2(X0.w, J0.w, m);
            m = dot2(X1.x, J1.x, m); m = dot2(X1.y, J1.y, m);
            m = dot2(X1.z, J1.z, m); m = dot2(X1.w, J1.w, m);
            const float dD = 1.f - h2f(ou);
            d_lds[l] = dD * m;
            dD_lds[l] = dD;
        }
        asm volatile("s_waitcnt lgkmcnt(0)" ::: "memory");
        __builtin_amdgcn_s_barrier();

        if (tc + 1 < S) {   // prefetch next step
            const unsigned char* rp = G + (row0 + tc + 1) * ROWB;
            A0n = *(const uint4*)(rp + 2048 + l4 * 1024 + (wv * 16 + l15) * 16);
            A1n = *(const uint4*)(rp + 2048 + (4 + l4) * 1024 + (wv * 16 + l15) * 16);
            if (wv == 0) {
                J0n = *(const uint4*)(rp + l * 16);
                J1n = *(const uint4*)(rp + 1024 + l * 16);
                on_ = *(const ushort*)(rp + 10240 + l * 16);
            }
        }

        // P_new = A * P_old (K=64 via two K=32 mfma), then D-scale, +d col64
        const f16x8 a0 = __builtin_bit_cast(f16x8, A0);
        const f16x8 a1 = __builtin_bit_cast(f16x8, A1);
        f32x4 dn[5];
        #pragma unroll
        for (int ct = 0; ct < 5; ++ct) {
            const f16x8 b0 = *(const f16x8*)(P_lds + l4 * 1296 + (ct * 16 + l15) * 16);
            const f16x8 b1 = *(const f16x8*)(P_lds + (4 + l4) * 1296 + (ct * 16 + l15) * 16);
            f32x4 z = {0.f, 0.f, 0.f, 0.f};
            z = __builtin_amdgcn_mfma_f32_16x16x32_f16(a0, b0, z, 0, 0, 0);
            z = __builtin_amdgcn_mfma_f32_16x16x32_f16(a1, b1, z, 0, 0, 0);
            dn[ct] = z;
        }
        const int rb = wv * 16 + l4 * 4;
        const float dd0 = dD_lds[rb], dd1 = dD_lds[rb + 1];
        const float dd2 = dD_lds[rb + 2], dd3 = dD_lds[rb + 3];
        #pragma unroll
        for (int ct = 0; ct < 5; ++ct) {
            acc[ct][0] = dn[ct][0] * dd0; acc[ct][1] = dn[ct][1] * dd1;
            acc[ct][2] = dn[ct][2] * dd2; acc[ct][3] = dn[ct][3] * dd3;
        }
        if (l15 == 0) {     // col 64 = q: += d
            acc[4][0] += d_lds[rb];     acc[4][1] += d_lds[rb + 1];
            acc[4][2] += d_lds[rb + 2]; acc[4][3] += d_lds[rb + 3];
        }
        asm volatile("s_waitcnt lgkmcnt(0)" ::: "memory");
        __builtin_amdgcn_s_barrier();
    }

    // store P~ f16: [64 rows][72 cols] (cols 0..63 = P, col 64 = q)
    unsigned char* pb = ws + OP + (size_t)blockIdx.x * 9216;
    #pragma unroll
    for (int ct = 0; ct < 5; ++ct) {
        if (ct == 4 && l15 != 0) continue;
        #pragma unroll
        for (int j = 0; j < 4; ++j) {
            const int r = wv * 16 + l4 * 4 + j, c = ct * 16 + l15;
            *(_Float16*)(pb + r * 144 + c * 2) = (_Float16)acc[ct][j];
        }
    }
}

// ---------------------------------------------------------------------------
// Prop: per batch (64 blocks, 1 wave), serially apply the 8 block maps:
// c_in(blk+1) = P(blk) c_in(blk) + q(blk). Stores c_in per block (f16).
// ---------------------------------------------------------------------------
__global__ __launch_bounds__(64, 1) void prop_kernel(unsigned char* ws)
{
    const int b = blockIdx.x, l = threadIdx.x;
    __shared__ __align__(16) unsigned cpk[32];

    _Float16* OCp = (_Float16*)(ws + OC);
    float cn = 0.f;
    if (l < 32) cpk[l] = 0;
    asm volatile("s_waitcnt lgkmcnt(0)" ::: "memory");

    for (int blk = 0; blk < NBLK; ++blk) {
        OCp[(size_t)(b * NBLK + blk) * 64 + l] = (_Float16)cn;
        if (blk == NBLK - 1) break;

        const unsigned char* prow = ws + OP + (size_t)(b * NBLK + blk) * 9216 + l * 144;
        uint4 p[8];
        #pragma unroll
        for (int i = 0; i < 8; ++i) p[i] = *(const uint4*)(prow + i * 16);
        const float q = h2f(*(const ushort*)(prow + 128));

        const uint4 C0 = ((const uint4*)cpk)[0], C1 = ((const uint4*)cpk)[1];
        const uint4 C2 = ((const uint4*)cpk)[2], C3 = ((const uint4*)cpk)[3];
        const uint4 C4 = ((const uint4*)cpk)[4], C5 = ((const uint4*)cpk)[5];
        const uint4 C6 = ((const uint4*)cpk)[6], C7 = ((const uint4*)cpk)[7];

        float a0 = q, a1 = 0.f, a2 = 0.f, a3 = 0.f;
        a0 = dot2(C0.x, p[0].x, a0); a0 = dot2(C0.y, p[0].y, a0);
        a0 = dot2(C0.z, p[0].z, a0); a0 = dot2(C0.w, p[0].w, a0);
        a1 = dot2(C1.x, p[1].x, a1); a1 = dot2(C1.y, p[1].y, a1);
        a1 = dot2(C1.z, p[1].z, a1); a1 = dot2(C1.w, p[1].w, a1);
        a2 = dot2(C2.x, p[2].x, a2); a2 = dot2(C2.y, p[2].y, a2);
        a2 = dot2(C2.z, p[2].z, a2); a2 = dot2(C2.w, p[2].w, a2);
        a3 = dot2(C3.x, p[3].x, a3); a3 = dot2(C3.y, p[3].y, a3);
        a3 = dot2(C3.z, p[3].z, a3); a3 = dot2(C3.w, p[3].w, a3);
        a0 = dot2(C4.x, p[4].x, a0); a0 = dot2(C4.y, p[4].y, a0);
        a0 = dot2(C4.z, p[4].z, a0); a0 = dot2(C4.w, p[4].w, a0);
        a1 = dot2(C5.x, p[5].x, a1); a1 = dot2(C5.y, p[5].y, a1);
        a1 = dot2(C5.z, p[5].z, a1); a1 = dot2(C5.w, p[5].w, a1);
        a2 = dot2(C6.x, p[6].x, a2); a2 = dot2(C6.y, p[6].y, a2);
        a2 = dot2(C6.z, p[6].z, a2); a2 = dot2(C6.w, p[6].w, a2);
        a3 = dot2(C7.x, p[7].x, a3); a3 = dot2(C7.y, p[7].y, a3);
        a3 = dot2(C7.z, p[7].z, a3); a3 = dot2(C7.w, p[7].w, a3);
        cn = (a0 + a1) + (a2 + a3);

        asm volatile("s_waitcnt lgkmcnt(0)" ::: "memory");
        __builtin_amdgcn_sched_barrier(0);
        ((_Float16*)cpk)[l] = (_Float16)cn;
        asm volatile("s_waitcnt lgkmcnt(0)" ::: "memory");
        __builtin_amdgcn_sched_barrier(0);
    }
}

// ---------------------------------------------------------------------------
// Scan32 (R17 scan, 32-step blocks, 512-way parallel): lane = k, f16 dot2
// inner loop, depth-6 contiguous DMA with exact counted vmcnt.
// ---------------------------------------------------------------------------
__global__ __launch_bounds__(64, 1) void scan_kernel(
    const unsigned char* __restrict__ ws,
    const float* __restrict__ Wfc, const float* __restrict__ bfc,
    float* __restrict__ out)
{
    const int b = blockIdx.x >> 3, blk = blockIdx.x & 7;
    const int l = threadIdx.x;
    const int t00 = blk * S;
    const unsigned char* G = ws + OG;

    __shared__ __align__(16) unsigned char buf[6][ROWB];
    __shared__ __align__(16) unsigned xs[256];
    __shared__ __align__(16) unsigned c_pk[32];

    float* cbase = out + B;

    if (l < 64)   // stage x_m window (1KB)
        ((uint4*)xs)[l] = ((const uint4*)(ws + OXM + ((size_t)b * T + t00) * 32))[l];
    if (l < 32)
        c_pk[l] = *(const unsigned*)(ws + OC + (size_t)blockIdx.x * 128 + l * 4);
    const float wfck = Wfc[l];
    const float bfc0 = bfc[0];
    asm volatile("s_waitcnt vmcnt(0) lgkmcnt(0)" ::: "memory");

#define DMA(tc_, bi_)                                                           \
    {                                                                           \
        const unsigned char* rp_ = G + ((size_t)b * T + t00 + (tc_)) * ROWB;    \
        unsigned char* lb_ = &buf[bi_][0];                                      \
        _Pragma("unroll")                                                       \
        for (int i_ = 0; i_ < 11; ++i_)                                         \
            __builtin_amdgcn_global_load_lds(                                   \
                (const __attribute__((address_space(1))) unsigned int*)         \
                    (rp_ + i_ * 1024 + l * 16),                                 \
                (__attribute__((address_space(3))) unsigned int*)               \
                    (lb_ + i_ * 1024), 16, 0, 0);                               \
    }

    DMA(0, 0); DMA(1, 1); DMA(2, 2); DMA(3, 3); DMA(4, 4); DMA(5, 5);

    const uint4* cq = (const uint4*)c_pk;
    const uint4* xq = (const uint4*)xs;
    int bi = 0;

    for (int tc = 0; tc < S; ++tc) {
        const int rem = (S - 1) - tc;
        if (tc >= 5) {
            if      (rem >= 5) vmwait<60>();
            else if (rem == 4) vmwait<49>();
            else if (rem == 3) vmwait<38>();
            else if (rem == 2) vmwait<27>();
            else if (rem == 1) vmwait<16>();
            else               vmwait<5>();
        } else {
            if      (tc == 0) vmwait<55>();
            else if (tc == 1) vmwait<56>();
            else if (tc == 2) vmwait<57>();
            else if (tc == 3) vmwait<58>();
            else              vmwait<59>();
        }
        __builtin_amdgcn_sched_barrier(0);

        const unsigned char* bp = &buf[bi][0];

        const uint4 J0 = *(const uint4*)(bp + l * 16);
        const uint4 J1 = *(const uint4*)(bp + 1024 + l * 16);
        const uint4 R0 = *(const uint4*)(bp + 2048 + l * 16);
        const uint4 R1 = *(const uint4*)(bp + 3072 + l * 16);
        const uint4 R2 = *(const uint4*)(bp + 4096 + l * 16);
        const uint4 R3 = *(const uint4*)(bp + 5120 + l * 16);
        const uint4 R4 = *(const uint4*)(bp + 6144 + l * 16);
        const uint4 R5 = *(const uint4*)(bp + 7168 + l * 16);
        const uint4 R6 = *(const uint4*)(bp + 8192 + l * 16);
        const uint4 R7 = *(const uint4*)(bp + 9216 + l * 16);
        const float o = h2f(*(const ushort*)(bp + 10240 + l * 16));

        const uint4 X0 = xq[tc * 2], X1 = xq[tc * 2 + 1];
        const uint4 C0 = cq[0], C1 = cq[1], C2 = cq[2], C3 = cq[3];
        const uint4 C4 = cq[4], C5 = cq[5], C6 = cq[6], C7 = cq[7];

        float a0 = 0.f, a1 = 0.f, a2 = 0.f, a3 = 0.f;
        a0 = dot2(X0.x, J0.x, a0); a0 = dot2(X0.y, J0.y, a0);
        a0 = dot2(X0.z, J0.z, a0); a0 = dot2(X0.w, J0.w, a0);
        a1 = dot2(X1.x, J1.x, a1); a1 = dot2(X1.y, J1.y, a1);
        a1 = dot2(X1.z, J1.z, a1); a1 = dot2(X1.w, J1.w, a1);
        a0 = dot2(C0.x, R0.x, a0); a0 = dot2(C0.y, R0.y, a0);
        a0 = dot2(C0.z, R0.z, a0); a0 = dot2(C0.w, R0.w, a0);
        a0 = dot2(C1.x, R1.x, a0); a0 = dot2(C1.y, R1.y, a0);
        a0 = dot2(C1.z, R1.z, a0); a0 = dot2(C1.w, R1.w, a0);
        a1 = dot2(C2.x, R2.x, a1); a1 = dot2(C2.y, R2.y, a1);
        a1 = dot2(C2.z, R2.z, a1); a1 = dot2(C2.w, R2.w, a1);
        a1 = dot2(C3.x, R3.x, a1); a1 = dot2(C3.y, R3.y, a1);
        a1 = dot2(C3.z, R3.z, a1); a1 = dot2(C3.w, R3.w, a1);
        a2 = dot2(C4.x, R4.x, a2); a2 = dot2(C4.y, R4.y, a2);
        a2 = dot2(C4.z, R4.z, a2); a2 = dot2(C4.w, R4.w, a2);
        a2 = dot2(C5.x, R5.x, a2); a2 = dot2(C5.y, R5.y, a2);
        a2 = dot2(C5.z, R5.z, a2); a2 = dot2(C5.w, R5.w, a2);
        a3 = dot2(C6.x, R6.x, a3); a3 = dot2(C6.y, R6.y, a3);
        a3 = dot2(C6.z, R6.z, a3); a3 = dot2(C6.w, R6.w, a3);
        a3 = dot2(C7.x, R7.x, a3); a3 = dot2(C7.y, R7.y, a3);
        a3 = dot2(C7.z, R7.z, a3); a3 = dot2(C7.w, R7.w, a3);

        const float m_new = (a0 + a1) + (a2 + a3);
        const float cn = (1.f - o) * m_new;

        cbase[((size_t)b * T + t00 + tc) * H + l] = cn;
        ((_Float16*)c_pk)[l] = (_Float16)cn;

        if (blk == NBLK - 1 && tc == S - 1) {
            float v = o * m_new * wfck;
            v += __shfl_xor(v, 1);  v += __shfl_xor(v, 2);
            v += __shfl_xor(v, 4);  v += __shfl_xor(v, 8);
            v += __shfl_xor(v, 16); v += __shfl_xor(v, 32);
            if (l == 0) out[b] = v + bfc0;
        }

        asm volatile("s_waitcnt lgkmcnt(0)" ::: "memory");
        __builtin_amdgcn_sched_barrier(0);

        if (tc + 6 < S) DMA(tc + 6, bi);
        bi = (bi == 5) ? 0 : bi + 1;
    }
#undef DMA
}

// ---------------------------------------------------------------------------
extern "C" void kernel_launch(void* const* d_in, const int* in_sizes, int n_in,
                              void* d_out, int out_size, void* d_ws, size_t ws_size,
                              hipStream_t stream) {
    const float* x_m = (const float*)d_in[0];
    const float* x_a = (const float*)d_in[1];
    const float* Wj  = (const float*)d_in[2];
    const float* bj  = (const float*)d_in[3];
    const float* Wr  = (const float*)d_in[4];
    const float* br  = (const float*)d_in[5];
    const float* Wo  = (const float*)d_in[6];
    const float* bo  = (const float*)d_in[7];
    const float* Wfc = (const float*)d_in[8];
    const float* bfc = (const float*)d_in[9];
    float* out = (float*)d_out;
    unsigned char* ws = (unsigned char*)d_ws;

    {   // conversions: W,x_a->bf16; x_m->f16; bias concat
        const int total = 5184 * 32 + B * T * A + B * T * M + 5184;
        prep_kernel<<<(total + 255) / 256, 256, 0, stream>>>(
            x_a, x_m, Wj, Wr, Wo, bj, br, bo, ws);
    }
    gate_kernel<<<(B * T) / 16, 128, 0, stream>>>(ws);
    compose_kernel<<<B * NBLK, 256, 0, stream>>>(ws);
    prop_kernel<<<B, 64, 0, stream>>>(ws);
    scan_kernel<<<B * NBLK, 64, 0, stream>>>(ws, Wfc, bfc, out);
}

// Round 19
// 106.994 us; speedup vs baseline: 4.3872x; 1.0955x over previous
//
#include <hip/hip_runtime.h>

// Problem constants (match reference setup_inputs)
constexpr int B = 64, T = 256, M = 16, A = 32, H = 64;
constexpr int ROWB = 8448;    // G row: 8 x 1KB R-octets + 256B (m_in,o) granule
constexpr int S = 32;         // time-block length
constexpr int NBLK = T / S;   // 8

typedef __attribute__((ext_vector_type(8))) short bf16x8;
typedef __attribute__((ext_vector_type(4))) float f32x4;
typedef _Float16 half2 __attribute__((ext_vector_type(2)));
typedef __fp16 fp16x2 __attribute__((ext_vector_type(2)));
typedef _Float16 f16x8 __attribute__((ext_vector_type(8)));

// ws layout
constexpr size_t OW  = 0;              // W  bf16 [5184][32]
constexpr size_t OX  = 332800;         // x_a bf16 [B*T][32]
constexpr size_t OB  = 1381376;        // bias f32 [5184]
constexpr size_t OXM = 1402880;        // x_m f16 [B*T][16]
constexpr size_t OG  = 1927168;        // G rows
constexpr size_t OP  = OG + (size_t)B * T * ROWB;        // P~ f16 [512][64][72]
constexpr size_t OC  = OP + (size_t)B * NBLK * 64 * 144; // c_in f16 [512][64]

// G row layout (f16):
//   [0, 8KB):    R-oct ro: granule k (16B) holds R[h=ro*8..ro*8+7][k]
//   [8KB,8.25KB): word k (4B) = (f16 m_in[k], f16 o[k])

template<int N> __device__ __forceinline__ void vmwait() {
    asm volatile("s_waitcnt vmcnt(%0)" :: "n"(N) : "memory");
}
__device__ __forceinline__ float dot2(unsigned a, unsigned b, float c) {
    return __builtin_amdgcn_fdot2(__builtin_bit_cast(half2, a),
                                  __builtin_bit_cast(half2, b), c, false);
}
__device__ __forceinline__ unsigned pkrtz(float a, float b) {
    fp16x2 pk = __builtin_amdgcn_cvt_pkrtz(a, b);
    return __builtin_bit_cast(unsigned, pk);
}
__device__ __forceinline__ float h2f(unsigned u) {
    return (float)__builtin_bit_cast(_Float16, (unsigned short)(u & 0xffffu));
}

// ---------------------------------------------------------------------------
// Prep: W,x_a -> bf16 (RNE); x_m -> f16; biases -> f32 concat.
// ---------------------------------------------------------------------------
__global__ __launch_bounds__(256) void prep_kernel(
    const float* __restrict__ x_a, const float* __restrict__ x_m,
    const float* __restrict__ Wj, const float* __restrict__ Wr,
    const float* __restrict__ Wo,
    const float* __restrict__ bj, const float* __restrict__ br,
    const float* __restrict__ bo, unsigned char* ws)
{
    const int nW = 5184 * 32, nX = B * T * A, nXM = B * T * M, nB = 5184;
    int idx = blockIdx.x * 256 + threadIdx.x;
    if (idx >= nW + nX + nXM + nB) return;
    if (idx < nW + nX) {
        float v; ushort* dst;
        if (idx < nW) {
            int row = idx >> 5;
            v = (row < 1024) ? Wj[idx] : (row < 5120) ? Wr[idx - 1024 * 32] : Wo[idx - 5120 * 32];
            dst = (ushort*)(ws + OW) + idx;
        } else {
            v = x_a[idx - nW];
            dst = (ushort*)(ws + OX) + (idx - nW);
        }
        unsigned u = __builtin_bit_cast(unsigned, v);
        *dst = (ushort)((u + 0x7fffu + ((u >> 16) & 1u)) >> 16);   // RNE
    } else if (idx < nW + nX + nXM) {
        int j = idx - nW - nX;
        ((_Float16*)(ws + OXM))[j] = (_Float16)x_m[j];
    } else {
        int row = idx - nW - nX - nXM;
        float v = (row < 1024) ? bj[row] : (row < 5120) ? br[row - 1024] : bo[row - 5120];
        ((float*)(ws + OB))[row] = v;
    }
}

// ---------------------------------------------------------------------------
// Gate kernel: 2 waves, 16 rows/block, grid = B*T/16. J groups folded into
// m_in inside the kernel (f32); row stores = 8 R-octets (1KB runs) + one
// 256B (m_in,o) granule. 27% fewer G bytes than R18.
// ---------------------------------------------------------------------------
__global__ __launch_bounds__(128) void gate_kernel(unsigned char* ws)
{
    const int tid = threadIdx.x, l = tid & 63, wv = tid >> 6;
    const int l15 = l & 15, l4 = l >> 4;
    const ushort* Wb = (const ushort*)(ws + OW);
    const ushort* xb = (const ushort*)(ws + OX);
    const float*  bc = (const float*)(ws + OB);
    unsigned char* G = ws + OG;

    __shared__ __align__(16) unsigned char tile[2 * 16 * 1040];  // 32.5KB
    __shared__ __align__(16) float pml[1024];                    // m_in f32 [16t][64k]
    __shared__ _Float16 ol[1024];                                // o f16 [16t][64k]
    __shared__ _Float16 xm_lds[256];                             // x_m [16t][16m]
    unsigned char* wtile = tile + wv * 16 * 1040;

    const int r0 = blockIdx.x * 16;                 // global row = b*T + t
    const bf16x8 bx = *(const bf16x8*)(xb + (size_t)(r0 + l15) * 32 + l4 * 8);
    const f32x4 zero = {0.f, 0.f, 0.f, 0.f};

    {   // stage x_m tile (512B): 128 threads x 4B
        ((unsigned*)xm_lds)[tid] = ((const unsigned*)(ws + OXM + (size_t)r0 * 32))[tid];
    }
    __syncthreads();

    // ---- J phase: 8 groups per wave, accumulate m_in partial in f32 ----
    float xmr[8];
    #pragma unroll
    for (int ji = 0; ji < 8; ++ji)
        xmr[ji] = (float)xm_lds[l15 * 16 + wv * 8 + ji];

    float pm[4][4];
    #pragma unroll
    for (int ct = 0; ct < 4; ++ct)
        #pragma unroll
        for (int j = 0; j < 4; ++j) pm[ct][j] = 0.f;

    #pragma unroll
    for (int ji = 0; ji < 8; ++ji) {
        const int g = wv * 8 + ji;
        f32x4 d[4];
        #pragma unroll
        for (int ct = 0; ct < 4; ++ct) {
            const bf16x8 aW = *(const bf16x8*)(
                Wb + (size_t)(g * 64 + ct * 16 + l15) * 32 + l4 * 8);
            d[ct] = __builtin_amdgcn_mfma_f32_16x16x32_bf16(aW, bx, zero, 0, 0, 0);
            const float4 bv = *(const float4*)(bc + g * 64 + ct * 16 + l4 * 4);
            d[ct][0] += bv.x; d[ct][1] += bv.y; d[ct][2] += bv.z; d[ct][3] += bv.w;
        }
        float sm = 0.f;
        #pragma unroll
        for (int ct = 0; ct < 4; ++ct)
            #pragma unroll
            for (int j = 0; j < 4; ++j) { d[ct][j] = __expf(d[ct][j]); sm += d[ct][j]; }
        sm += __shfl_xor(sm, 16); sm += __shfl_xor(sm, 32);
        const float inv = __fdividef(xmr[ji], sm);   // fold x_m into the scale
        #pragma unroll
        for (int ct = 0; ct < 4; ++ct)
            #pragma unroll
            for (int j = 0; j < 4; ++j) pm[ct][j] += inv * d[ct][j];
    }

    // ---- o phase (wave1) + pm combine via LDS ----
    if (wv == 1) {
        f32x4 d[4];
        #pragma unroll
        for (int ct = 0; ct < 4; ++ct) {
            const bf16x8 aW = *(const bf16x8*)(
                Wb + (size_t)(80 * 64 + ct * 16 + l15) * 32 + l4 * 8);
            d[ct] = __builtin_amdgcn_mfma_f32_16x16x32_bf16(aW, bx, zero, 0, 0, 0);
            const float4 bv = *(const float4*)(bc + 80 * 64 + ct * 16 + l4 * 4);
            d[ct][0] += bv.x; d[ct][1] += bv.y; d[ct][2] += bv.z; d[ct][3] += bv.w;
            #pragma unroll
            for (int j = 0; j < 4; ++j) {
                const int gc = ct * 16 + l4 * 4 + j;
                ol[l15 * 64 + gc] =
                    (_Float16)__fdividef(1.f, 1.f + __expf(-d[ct][j]));
            }
        }
    } else {    // wave0 writes its pm partial
        #pragma unroll
        for (int ct = 0; ct < 4; ++ct)
            *(float4*)&pml[l15 * 64 + ct * 16 + l4 * 4] =
                make_float4(pm[ct][0], pm[ct][1], pm[ct][2], pm[ct][3]);
    }
    __syncthreads();
    if (wv == 1) {   // wave1 adds its partial
        #pragma unroll
        for (int ct = 0; ct < 4; ++ct) {
            float4 v = *(const float4*)&pml[l15 * 64 + ct * 16 + l4 * 4];
            *(float4*)&pml[l15 * 64 + ct * 16 + l4 * 4] = make_float4(
                v.x + pm[ct][0], v.y + pm[ct][1], v.z + pm[ct][2], v.w + pm[ct][3]);
        }
    }
    __syncthreads();

    // ---- (m_in,o) granule store: 4B words, 256B runs per row ----
    #pragma unroll
    for (int i = 0; i < 8; ++i) {
        const int idx = i * 128 + tid;
        const int t = idx >> 6, k = idx & 63;
        *(unsigned*)(G + (size_t)(r0 + t) * ROWB + 8192 + k * 4) =
            pkrtz(pml[idx], (float)ol[idx]);
    }

    // ---- R phase: 4 octets per wave, tile transpose, 1KB-run stores ----
    for (int i = 0; i < 4; ++i) {
        const int ro = 2 * i + wv;
        f32x4 s[4];
        #pragma unroll
        for (int gi = 0; gi < 8; ++gi) {
            const int g = 16 + ro * 8 + gi;
            f32x4 d[4];
            #pragma unroll
            for (int ct = 0; ct < 4; ++ct) {
                const bf16x8 aW = *(const bf16x8*)(
                    Wb + (size_t)(g * 64 + ct * 16 + l15) * 32 + l4 * 8);
                d[ct] = __builtin_amdgcn_mfma_f32_16x16x32_bf16(aW, bx, zero, 0, 0, 0);
                const float4 bv = *(const float4*)(bc + g * 64 + ct * 16 + l4 * 4);
                d[ct][0] += bv.x; d[ct][1] += bv.y; d[ct][2] += bv.z; d[ct][3] += bv.w;
            }
            float sm = 0.f;
            #pragma unroll
            for (int ct = 0; ct < 4; ++ct)
                #pragma unroll
                for (int j = 0; j < 4; ++j) { d[ct][j] = __expf(d[ct][j]); sm += d[ct][j]; }
            sm += __shfl_xor(sm, 16); sm += __shfl_xor(sm, 32);
            const float inv = __fdividef(1.f, sm);
            #pragma unroll
            for (int ct = 0; ct < 4; ++ct)
                #pragma unroll
                for (int j = 0; j < 4; ++j) d[ct][j] *= inv;

            if (gi & 1) {
                const int p = gi >> 1;
                #pragma unroll
                for (int ct = 0; ct < 4; ++ct)
                    #pragma unroll
                    for (int j = 0; j < 4; ++j) {
                        const int gc = ct * 16 + l4 * 4 + j;
                        *(unsigned*)(wtile + l15 * 1040 + gc * 16 + p * 4) =
                            pkrtz(s[ct][j], d[ct][j]);
                    }
            } else {
                #pragma unroll
                for (int ct = 0; ct < 4; ++ct) s[ct] = d[ct];
            }
        }

        asm volatile("s_waitcnt lgkmcnt(0)" ::: "memory");
        __builtin_amdgcn_sched_barrier(0);
        #pragma unroll
        for (int t = 0; t < 16; ++t) {
            uint4 v = *(const uint4*)(wtile + t * 1040 + l * 16);
            *(uint4*)(G + (size_t)(r0 + t) * ROWB + ro * 1024 + l * 16) = v;
        }
        asm volatile("s_waitcnt lgkmcnt(0)" ::: "memory");
        __builtin_amdgcn_sched_barrier(0);
    }
}

// ---------------------------------------------------------------------------
// Compose: per (b,blk) chain P~ <- A_t P~ (+d on col 64), A_t = D_t R_t^T.
// R-octet granules = MFMA A-fragments (per-lane b128 direct from G).
// d/dD come straight from the (m_in,o) granule.
// ---------------------------------------------------------------------------
__global__ __launch_bounds__(256, 2) void compose_kernel(unsigned char* ws)
{
    const int tid = threadIdx.x, l = tid & 63, wv = tid >> 6;
    const int l15 = l & 15, l4 = l >> 4;
    const unsigned char* G = ws + OG;

    __shared__ __align__(16) unsigned char P_lds[8 * 1296];
    __shared__ __align__(16) float d_lds[64];
    __shared__ __align__(16) float dD_lds[64];

    const int bb = blockIdx.x >> 3, blk = blockIdx.x & 7;
    const size_t row0 = (size_t)bb * T + blk * S;

    float acc[5][4];
    #pragma unroll
    for (int ct = 0; ct < 5; ++ct)
        #pragma unroll
        for (int j = 0; j < 4; ++j) {
            const int r = wv * 16 + l4 * 4 + j, c = ct * 16 + l15;
            acc[ct][j] = (r == c) ? 1.f : 0.f;
        }

    // prefetch step-0 global loads
    uint4 A0n, A1n; unsigned mon = 0;
    {
        const unsigned char* rp = G + row0 * ROWB;
        A0n = *(const uint4*)(rp + l4 * 1024 + (wv * 16 + l15) * 16);
        A1n = *(const uint4*)(rp + (4 + l4) * 1024 + (wv * 16 + l15) * 16);
        if (wv == 0) mon = *(const unsigned*)(rp + 8192 + l * 4);
    }

    for (int tc = 0; tc < S; ++tc) {
        const uint4 A0 = A0n, A1 = A1n;
        const unsigned mo = mon;

        // write P_{tc-1} (acc) into P_lds as f16 h-octet granules
        #pragma unroll
        for (int ct = 0; ct < 5; ++ct) {
            const int hoct = wv * 2 + (l4 >> 1);
            *(uint2*)(P_lds + hoct * 1296 + (ct * 16 + l15) * 16 + (l4 & 1) * 8) =
                make_uint2(pkrtz(acc[ct][0], acc[ct][1]), pkrtz(acc[ct][2], acc[ct][3]));
        }
        if (wv == 0) {    // d = (1-o)*m_in, dD = 1-o (lane l = row)
            const float dD = 1.f - h2f(mo >> 16);
            d_lds[l] = dD * h2f(mo);
            dD_lds[l] = dD;
        }
        asm volatile("s_waitcnt lgkmcnt(0)" ::: "memory");
        __builtin_amdgcn_s_barrier();

        if (tc + 1 < S) {   // prefetch next step
            const unsigned char* rp = G + (row0 + tc + 1) * ROWB;
            A0n = *(const uint4*)(rp + l4 * 1024 + (wv * 16 + l15) * 16);
            A1n = *(const uint4*)(rp + (4 + l4) * 1024 + (wv * 16 + l15) * 16);
            if (wv == 0) mon = *(const unsigned*)(rp + 8192 + l * 4);
        }

        const f16x8 a0 = __builtin_bit_cast(f16x8, A0);
        const f16x8 a1 = __builtin_bit_cast(f16x8, A1);
        f32x4 dn[5];
        #pragma unroll
        for (int ct = 0; ct < 5; ++ct) {
            const f16x8 b0 = *(const f16x8*)(P_lds + l4 * 1296 + (ct * 16 + l15) * 16);
            const f16x8 b1 = *(const f16x8*)(P_lds + (4 + l4) * 1296 + (ct * 16 + l15) * 16);
            f32x4 z = {0.f, 0.f, 0.f, 0.f};
            z = __builtin_amdgcn_mfma_f32_16x16x32_f16(a0, b0, z, 0, 0, 0);
            z = __builtin_amdgcn_mfma_f32_16x16x32_f16(a1, b1, z, 0, 0, 0);
            dn[ct] = z;
        }
        const int rb = wv * 16 + l4 * 4;
        const float dd0 = dD_lds[rb], dd1 = dD_lds[rb + 1];
        const float dd2 = dD_lds[rb + 2], dd3 = dD_lds[rb + 3];
        #pragma unroll
        for (int ct = 0; ct < 5; ++ct) {
            acc[ct][0] = dn[ct][0] * dd0; acc[ct][1] = dn[ct][1] * dd1;
            acc[ct][2] = dn[ct][2] * dd2; acc[ct][3] = dn[ct][3] * dd3;
        }
        if (l15 == 0) {     // col 64 = q: += d
            acc[4][0] += d_lds[rb];     acc[4][1] += d_lds[rb + 1];
            acc[4][2] += d_lds[rb + 2]; acc[4][3] += d_lds[rb + 3];
        }
        asm volatile("s_waitcnt lgkmcnt(0)" ::: "memory");
        __builtin_amdgcn_s_barrier();
    }

    // store P~ f16: [64 rows][72 cols] (cols 0..63 = P, col 64 = q)
    unsigned char* pb = ws + OP + (size_t)blockIdx.x * 9216;
    #pragma unroll
    for (int ct = 0; ct < 5; ++ct) {
        if (ct == 4 && l15 != 0) continue;
        #pragma unroll
        for (int j = 0; j < 4; ++j) {
            const int r = wv * 16 + l4 * 4 + j, c = ct * 16 + l15;
            *(_Float16*)(pb + r * 144 + c * 2) = (_Float16)acc[ct][j];
        }
    }
}

// ---------------------------------------------------------------------------
// Prop: per batch (64 blocks, 1 wave), serially apply the 8 block maps.
// ---------------------------------------------------------------------------
__global__ __launch_bounds__(64, 1) void prop_kernel(unsigned char* ws)
{
    const int b = blockIdx.x, l = threadIdx.x;
    __shared__ __align__(16) unsigned cpk[32];

    _Float16* OCp = (_Float16*)(ws + OC);
    float cn = 0.f;
    if (l < 32) cpk[l] = 0;
    asm volatile("s_waitcnt lgkmcnt(0)" ::: "memory");

    for (int blk = 0; blk < NBLK; ++blk) {
        OCp[(size_t)(b * NBLK + blk) * 64 + l] = (_Float16)cn;
        if (blk == NBLK - 1) break;

        const unsigned char* prow = ws + OP + (size_t)(b * NBLK + blk) * 9216 + l * 144;
        uint4 p[8];
        #pragma unroll
        for (int i = 0; i < 8; ++i) p[i] = *(const uint4*)(prow + i * 16);
        const float q = h2f(*(const ushort*)(prow + 128));

        const uint4 C0 = ((const uint4*)cpk)[0], C1 = ((const uint4*)cpk)[1];
        const uint4 C2 = ((const uint4*)cpk)[2], C3 = ((const uint4*)cpk)[3];
        const uint4 C4 = ((const uint4*)cpk)[4], C5 = ((const uint4*)cpk)[5];
        const uint4 C6 = ((const uint4*)cpk)[6], C7 = ((const uint4*)cpk)[7];

        float a0 = q, a1 = 0.f, a2 = 0.f, a3 = 0.f;
        a0 = dot2(C0.x, p[0].x, a0); a0 = dot2(C0.y, p[0].y, a0);
        a0 = dot2(C0.z, p[0].z, a0); a0 = dot2(C0.w, p[0].w, a0);
        a1 = dot2(C1.x, p[1].x, a1); a1 = dot2(C1.y, p[1].y, a1);
        a1 = dot2(C1.z, p[1].z, a1); a1 = dot2(C1.w, p[1].w, a1);
        a2 = dot2(C2.x, p[2].x, a2); a2 = dot2(C2.y, p[2].y, a2);
        a2 = dot2(C2.z, p[2].z, a2); a2 = dot2(C2.w, p[2].w, a2);
        a3 = dot2(C3.x, p[3].x, a3); a3 = dot2(C3.y, p[3].y, a3);
        a3 = dot2(C3.z, p[3].z, a3); a3 = dot2(C3.w, p[3].w, a3);
        a0 = dot2(C4.x, p[4].x, a0); a0 = dot2(C4.y, p[4].y, a0);
        a0 = dot2(C4.z, p[4].z, a0); a0 = dot2(C4.w, p[4].w, a0);
        a1 = dot2(C5.x, p[5].x, a1); a1 = dot2(C5.y, p[5].y, a1);
        a1 = dot2(C5.z, p[5].z, a1); a1 = dot2(C5.w, p[5].w, a1);
        a2 = dot2(C6.x, p[6].x, a2); a2 = dot2(C6.y, p[6].y, a2);
        a2 = dot2(C6.z, p[6].z, a2); a2 = dot2(C6.w, p[6].w, a2);
        a3 = dot2(C7.x, p[7].x, a3); a3 = dot2(C7.y, p[7].y, a3);
        a3 = dot2(C7.z, p[7].z, a3); a3 = dot2(C7.w, p[7].w, a3);
        cn = (a0 + a1) + (a2 + a3);

        asm volatile("s_waitcnt lgkmcnt(0)" ::: "memory");
        __builtin_amdgcn_sched_barrier(0);
        ((_Float16*)cpk)[l] = (_Float16)cn;
        asm volatile("s_waitcnt lgkmcnt(0)" ::: "memory");
        __builtin_amdgcn_sched_barrier(0);
    }
}

// ---------------------------------------------------------------------------
// Scan32: 512 blocks x 1 wave, lane = k. Per step: 8 R b128 + 1 granule b32
// reads, 32 dot2; DMA 9 ops/batch (8x16B/lane + 1x4B/lane), depth-6, exact
// counted vmcnt (steady 50 = 45 loads + 5 stores).
// ---------------------------------------------------------------------------
__global__ __launch_bounds__(64, 1) void scan_kernel(
    const unsigned char* __restrict__ ws,
    const float* __restrict__ Wfc, const float* __restrict__ bfc,
    float* __restrict__ out)
{
    const int b = blockIdx.x >> 3, blk = blockIdx.x & 7;
    const int l = threadIdx.x;
    const int t00 = blk * S;
    const unsigned char* G = ws + OG;

    __shared__ __align__(16) unsigned char buf[6][ROWB];   // 50.7KB
    __shared__ __align__(16) unsigned c_pk[32];

    float* cbase = out + B;

    if (l < 32)
        c_pk[l] = *(const unsigned*)(ws + OC + (size_t)blockIdx.x * 128 + l * 4);
    const float wfck = Wfc[l];
    const float bfc0 = bfc[0];
    asm volatile("s_waitcnt vmcnt(0) lgkmcnt(0)" ::: "memory");

#define DMA(tc_, bi_)                                                           \
    {                                                                           \
        const unsigned char* rp_ = G + ((size_t)b * T + t00 + (tc_)) * ROWB;    \
        unsigned char* lb_ = &buf[bi_][0];                                      \
        _Pragma("unroll")                                                       \
        for (int i_ = 0; i_ < 8; ++i_)                                          \
            __builtin_amdgcn_global_load_lds(                                   \
                (const __attribute__((address_space(1))) unsigned int*)         \
                    (rp_ + i_ * 1024 + l * 16),                                 \
                (__attribute__((address_space(3))) unsigned int*)               \
                    (lb_ + i_ * 1024), 16, 0, 0);                               \
        __builtin_amdgcn_global_load_lds(                                       \
            (const __attribute__((address_space(1))) unsigned int*)             \
                (rp_ + 8192 + l * 4),                                           \
            (__attribute__((address_space(3))) unsigned int*)                   \
                (lb_ + 8192), 4, 0, 0);                                         \
    }

    DMA(0, 0); DMA(1, 1); DMA(2, 2); DMA(3, 3); DMA(4, 4); DMA(5, 5);

    const uint4* cq = (const uint4*)c_pk;
    int bi = 0;

    for (int tc = 0; tc < S; ++tc) {
        if (tc >= 6) {
            const int rem = (S - 1) - tc;
            if      (rem >= 5) vmwait<50>();
            else if (rem == 4) vmwait<41>();
            else if (rem == 3) vmwait<32>();
            else if (rem == 2) vmwait<23>();
            else if (rem == 1) vmwait<14>();
            else               vmwait<5>();
        } else {
            if      (tc == 0) vmwait<45>();
            else if (tc == 1) vmwait<46>();
            else if (tc == 2) vmwait<47>();
            else if (tc == 3) vmwait<48>();
            else if (tc == 4) vmwait<49>();
            else              vmwait<50>();
        }
        __builtin_amdgcn_sched_barrier(0);

        const unsigned char* bp = &buf[bi][0];

        const uint4 R0 = *(const uint4*)(bp + 0    + l * 16);
        const uint4 R1 = *(const uint4*)(bp + 1024 + l * 16);
        const uint4 R2 = *(const uint4*)(bp + 2048 + l * 16);
        const uint4 R3 = *(const uint4*)(bp + 3072 + l * 16);
        const uint4 R4 = *(const uint4*)(bp + 4096 + l * 16);
        const uint4 R5 = *(const uint4*)(bp + 5120 + l * 16);
        const uint4 R6 = *(const uint4*)(bp + 6144 + l * 16);
        const uint4 R7 = *(const uint4*)(bp + 7168 + l * 16);
        const unsigned mo = *(const unsigned*)(bp + 8192 + l * 4);
        const float o = h2f(mo >> 16);

        const uint4 C0 = cq[0], C1 = cq[1], C2 = cq[2], C3 = cq[3];
        const uint4 C4 = cq[4], C5 = cq[5], C6 = cq[6], C7 = cq[7];

        float a0 = h2f(mo), a1 = 0.f, a2 = 0.f, a3 = 0.f;   // a0 seeds m_in
        a0 = dot2(C0.x, R0.x, a0); a0 = dot2(C0.y, R0.y, a0);
        a0 = dot2(C0.z, R0.z, a0); a0 = dot2(C0.w, R0.w, a0);
        a0 = dot2(C1.x, R1.x, a0); a0 = dot2(C1.y, R1.y, a0);
        a0 = dot2(C1.z, R1.z, a0); a0 = dot2(C1.w, R1.w, a0);
        a1 = dot2(C2.x, R2.x, a1); a1 = dot2(C2.y, R2.y, a1);
        a1 = dot2(C2.z, R2.z, a1); a1 = dot2(C2.w, R2.w, a1);
        a1 = dot2(C3.x, R3.x, a1); a1 = dot2(C3.y, R3.y, a1);
        a1 = dot2(C3.z, R3.z, a1); a1 = dot2(C3.w, R3.w, a1);
        a2 = dot2(C4.x, R4.x, a2); a2 = dot2(C4.y, R4.y, a2);
        a2 = dot2(C4.z, R4.z, a2); a2 = dot2(C4.w, R4.w, a2);
        a2 = dot2(C5.x, R5.x, a2); a2 = dot2(C5.y, R5.y, a2);
        a2 = dot2(C5.z, R5.z, a2); a2 = dot2(C5.w, R5.w, a2);
        a3 = dot2(C6.x, R6.x, a3); a3 = dot2(C6.y, R6.y, a3);
        a3 = dot2(C6.z, R6.z, a3); a3 = dot2(C6.w, R6.w, a3);
        a3 = dot2(C7.x, R7.x, a3); a3 = dot2(C7.y, R7.y, a3);
        a3 = dot2(C7.z, R7.z, a3); a3 = dot2(C7.w, R7.w, a3);

        const float m_new = (a0 + a1) + (a2 + a3);
        const float cn = (1.f - o) * m_new;

        cbase[((size_t)b * T + t00 + tc) * H + l] = cn;
        ((_Float16*)c_pk)[l] = (_Float16)cn;

        if (blk == NBLK - 1 && tc == S - 1) {
            float v = o * m_new * wfck;
            v += __shfl_xor(v, 1);  v += __shfl_xor(v, 2);
            v += __shfl_xor(v, 4);  v += __shfl_xor(v, 8);
            v += __shfl_xor(v, 16); v += __shfl_xor(v, 32);
            if (l == 0) out[b] = v + bfc0;
        }

        asm volatile("s_waitcnt lgkmcnt(0)" ::: "memory");
        __builtin_amdgcn_sched_barrier(0);

        if (tc + 6 < S) DMA(tc + 6, bi);
        bi = (bi == 5) ? 0 : bi + 1;
    }
#undef DMA
}

// ---------------------------------------------------------------------------
extern "C" void kernel_launch(void* const* d_in, const int* in_sizes, int n_in,
                              void* d_out, int out_size, void* d_ws, size_t ws_size,
                              hipStream_t stream) {
    const float* x_m = (const float*)d_in[0];
    const float* x_a = (const float*)d_in[1];
    const float* Wj  = (const float*)d_in[2];
    const float* bj  = (const float*)d_in[3];
    const float* Wr  = (const float*)d_in[4];
    const float* br  = (const float*)d_in[5];
    const float* Wo  = (const float*)d_in[6];
    const float* bo  = (const float*)d_in[7];
    const float* Wfc = (const float*)d_in[8];
    const float* bfc = (const float*)d_in[9];
    float* out = (float*)d_out;
    unsigned char* ws = (unsigned char*)d_ws;

    {   // conversions: W,x_a->bf16; x_m->f16; bias concat
        const int total = 5184 * 32 + B * T * A + B * T * M + 5184;
        prep_kernel<<<(total + 255) / 256, 256, 0, stream>>>(
            x_a, x_m, Wj, Wr, Wo, bj, br, bo, ws);
    }
    gate_kernel<<<(B * T) / 16, 128, 0, stream>>>(ws);
    compose_kernel<<<B * NBLK, 256, 0, stream>>>(ws);
    prop_kernel<<<B, 64, 0, stream>>>(ws);
    scan_kernel<<<B * NBLK, 64, 0, stream>>>(ws, Wfc, bfc, out);
}